// Round 1
// baseline (590.189 us; speedup 1.0000x reference)
//
#include <hip/hip_runtime.h>
#include <hip/hip_bf16.h>
#include <cmath>

#define B_   2
#define T_   4096
#define E_   768
#define NH_  12
#define HS_  64
#define QKV_ROW (3 * E_)   // 2304

typedef __attribute__((ext_vector_type(8))) short bf16x8;
typedef __attribute__((ext_vector_type(4))) float f32x4;

__device__ __forceinline__ unsigned short f2bf(float f) {
    unsigned int u = __builtin_bit_cast(unsigned int, f);
    u = (u + 0x7FFFu + ((u >> 16) & 1u)) >> 16;
    return (unsigned short)u;
}

// ---------------------------------------------------------------------------
// GEMM: C[M,N] = A[M,K] (fp32) @ B[K,N] (fp32) + bias[N]
// 128x128 block tile, 4 waves (2x2), each wave 64x64 via 4x4 mfma 16x16x32 bf16
// ---------------------------------------------------------------------------
template<bool OUT_BF16>
__global__ __launch_bounds__(256) void gemm_bias_kernel(
    const float* __restrict__ A, const float* __restrict__ Bm,
    const float* __restrict__ bias, void* __restrict__ Cout,
    int M, int N, int K)
{
    __shared__ __align__(16) unsigned short As[128][40];  // [m][k] pad->80B rows
    __shared__ __align__(16) unsigned short Bt[128][40];  // [n][k] (B transposed)

    const int tid  = threadIdx.x;
    const int m0   = blockIdx.y * 128;
    const int n0   = blockIdx.x * 128;
    const int w    = tid >> 6;
    const int lane = tid & 63;
    const int lr   = lane & 15;
    const int lk   = lane >> 4;
    const int wm   = (w >> 1) * 64;
    const int wn   = (w & 1) * 64;

    f32x4 acc[4][4];
#pragma unroll
    for (int i = 0; i < 4; ++i)
#pragma unroll
        for (int j = 0; j < 4; ++j) acc[i][j] = (f32x4){0.f, 0.f, 0.f, 0.f};

    const int ar = tid >> 3;         // 0..31 (A row group)
    const int ak = (tid & 7) * 4;    // 0..28 (A k col)
    const int bn = (tid & 31) * 4;   // 0..124 (B n col)
    const int bk = tid >> 5;         // 0..7  (B k row group)

    for (int k0 = 0; k0 < K; k0 += 32) {
        // stage A tile 128x32 (fp32 -> bf16)
#pragma unroll
        for (int i = 0; i < 4; ++i) {
            const int row = ar + i * 32;
            const float4 v = *(const float4*)&A[(size_t)(m0 + row) * K + k0 + ak];
            ushort4 s;
            s.x = f2bf(v.x); s.y = f2bf(v.y); s.z = f2bf(v.z); s.w = f2bf(v.w);
            *(ushort4*)&As[row][ak] = s;
        }
        // stage B tile 32x128 transposed -> Bt[n][k]
#pragma unroll
        for (int i = 0; i < 4; ++i) {
            const int k = bk + i * 8;
            const float4 v = *(const float4*)&Bm[(size_t)(k0 + k) * N + n0 + bn];
            Bt[bn + 0][k] = f2bf(v.x);
            Bt[bn + 1][k] = f2bf(v.y);
            Bt[bn + 2][k] = f2bf(v.z);
            Bt[bn + 3][k] = f2bf(v.w);
        }
        __syncthreads();

        bf16x8 a[4], b[4];
#pragma unroll
        for (int i = 0; i < 4; ++i)
            a[i] = *(const bf16x8*)&As[wm + i * 16 + lr][lk * 8];
#pragma unroll
        for (int j = 0; j < 4; ++j)
            b[j] = *(const bf16x8*)&Bt[wn + j * 16 + lr][lk * 8];
#pragma unroll
        for (int i = 0; i < 4; ++i)
#pragma unroll
            for (int j = 0; j < 4; ++j)
                acc[i][j] = __builtin_amdgcn_mfma_f32_16x16x32_bf16(
                    a[i], b[j], acc[i][j], 0, 0, 0);
        __syncthreads();
    }

    // epilogue: C/D layout col = lane&15, row = (lane>>4)*4 + reg
#pragma unroll
    for (int i = 0; i < 4; ++i) {
#pragma unroll
        for (int j = 0; j < 4; ++j) {
#pragma unroll
            for (int r = 0; r < 4; ++r) {
                const int row = m0 + wm + i * 16 + lk * 4 + r;
                const int col = n0 + wn + j * 16 + lr;
                const float v = acc[i][j][r] + bias[col];
                if (OUT_BF16)
                    ((unsigned short*)Cout)[(size_t)row * N + col] = f2bf(v);
                else
                    ((float*)Cout)[(size_t)row * N + col] = v;
            }
        }
    }
}

// ---------------------------------------------------------------------------
// Flash attention (causal). Block = 64 q-rows of one (b, nh).
// 4 waves x 16 q-rows. KV tiles of 64. qkv is bf16 [B, T, 3, NH, HS].
// Writes y fp32 [B, T, E] (heads re-interleaved).
// ---------------------------------------------------------------------------
__global__ __launch_bounds__(256) void flash_kernel(
    const unsigned short* __restrict__ qkv, float* __restrict__ y)
{
    __shared__ __align__(16) unsigned short K_lds[64][72];     // [kv][hs]
    __shared__ __align__(16) unsigned short Vt[64][72];        // [hs][kv]
    __shared__ __align__(16) unsigned short P_lds[4][16][72];  // per-wave P

    const int tid  = threadIdx.x;
    const int w    = tid >> 6;
    const int lane = tid & 63;
    const int lr   = lane & 15;
    const int lk   = lane >> 4;
    const int qb   = blockIdx.x;
    const int head = blockIdx.y;
    const int b    = head / NH_;
    const int nh   = head % NH_;
    const int q0   = qb * 64;

    const unsigned short* qkv_b = qkv + (size_t)b * T_ * QKV_ROW;

    // Q fragments (A-layout: row = lane&15, k = (lane>>4)*8 + j)
    bf16x8 qf[2];
    {
        const int tq = q0 + w * 16 + lr;
        const unsigned short* qrow = qkv_b + (size_t)tq * QKV_ROW + nh * HS_;
        qf[0] = *(const bf16x8*)(qrow + lk * 8);
        qf[1] = *(const bf16x8*)(qrow + 32 + lk * 8);
    }

    f32x4 accy[4];
#pragma unroll
    for (int i = 0; i < 4; ++i) accy[i] = (f32x4){0.f, 0.f, 0.f, 0.f};
    float m[4], l[4];
#pragma unroll
    for (int r = 0; r < 4; ++r) { m[r] = -INFINITY; l[r] = 0.f; }

    const int sr = tid >> 2;          // 0..63 staging row (kv)
    const int sc = (tid & 3) * 16;    // staging col base (hs)

    for (int j = 0; j <= qb; ++j) {
        const int kv0 = j * 64;
        __syncthreads();  // protect K_lds/Vt of previous iteration
        {
            const unsigned short* krow =
                qkv_b + (size_t)(kv0 + sr) * QKV_ROW + E_ + nh * HS_ + sc;
            const unsigned short* vrow = krow + E_;
            int4 k01 = *(const int4*)krow;
            int4 k23 = *(const int4*)(krow + 8);
            *(int4*)&K_lds[sr][sc]     = k01;
            *(int4*)&K_lds[sr][sc + 8] = k23;
            int4 v01 = *(const int4*)vrow;
            int4 v23 = *(const int4*)(vrow + 8);
            const unsigned short* vs0 = (const unsigned short*)&v01;
            const unsigned short* vs1 = (const unsigned short*)&v23;
#pragma unroll
            for (int i = 0; i < 8; ++i) Vt[sc + i][sr] = vs0[i];
#pragma unroll
            for (int i = 0; i < 8; ++i) Vt[sc + 8 + i][sr] = vs1[i];
        }
        __syncthreads();

        // S = Q K^T  (16 q-rows x 64 kv-cols per wave)
        f32x4 s[4];
#pragma unroll
        for (int cb = 0; cb < 4; ++cb) {
            s[cb] = (f32x4){0.f, 0.f, 0.f, 0.f};
#pragma unroll
            for (int ks = 0; ks < 2; ++ks) {
                bf16x8 kf = *(const bf16x8*)&K_lds[cb * 16 + lr][ks * 32 + lk * 8];
                s[cb] = __builtin_amdgcn_mfma_f32_16x16x32_bf16(qf[ks], kf, s[cb], 0, 0, 0);
            }
        }
        const float scale = 0.125f;  // 1/sqrt(64)
        if (j == qb) {
#pragma unroll
            for (int cb = 0; cb < 4; ++cb) {
                const int tk = kv0 + cb * 16 + lr;
#pragma unroll
                for (int r = 0; r < 4; ++r) {
                    const int tq = q0 + w * 16 + lk * 4 + r;
                    const float v = s[cb][r] * scale;
                    s[cb][r] = (tk <= tq) ? v : -INFINITY;
                }
            }
        } else {
#pragma unroll
            for (int cb = 0; cb < 4; ++cb)
#pragma unroll
                for (int r = 0; r < 4; ++r) s[cb][r] *= scale;
        }

        // online softmax (row lives in 16 lanes sharing lane>>4 group? no:
        // row is fixed per (lk, r); the 16 kv-cols of the fragment are lanes
        // with the same lk, so reduce across lr via shfl_xor 1,2,4,8)
        float p[4][4];
#pragma unroll
        for (int r = 0; r < 4; ++r) {
            float mx = fmaxf(fmaxf(s[0][r], s[1][r]), fmaxf(s[2][r], s[3][r]));
            mx = fmaxf(mx, __shfl_xor(mx, 1));
            mx = fmaxf(mx, __shfl_xor(mx, 2));
            mx = fmaxf(mx, __shfl_xor(mx, 4));
            mx = fmaxf(mx, __shfl_xor(mx, 8));
            const float mnew  = fmaxf(m[r], mx);
            const float alpha = __expf(m[r] - mnew);
            m[r] = mnew;
            float rs = 0.f;
#pragma unroll
            for (int cb = 0; cb < 4; ++cb) {
                const float pv = __expf(s[cb][r] - mnew);
                p[cb][r] = pv;
                rs += pv;
            }
            rs += __shfl_xor(rs, 1);
            rs += __shfl_xor(rs, 2);
            rs += __shfl_xor(rs, 4);
            rs += __shfl_xor(rs, 8);
            l[r] = l[r] * alpha + rs;
#pragma unroll
            for (int cb = 0; cb < 4; ++cb) accy[cb][r] *= alpha;
        }

        // P (C-layout) -> LDS so PV can read A-layout fragments
#pragma unroll
        for (int cb = 0; cb < 4; ++cb)
#pragma unroll
            for (int r = 0; r < 4; ++r)
                P_lds[w][lk * 4 + r][cb * 16 + lr] = f2bf(p[cb][r]);
        __syncthreads();

        // Y += P @ V
#pragma unroll
        for (int cb = 0; cb < 4; ++cb) {
#pragma unroll
            for (int ks = 0; ks < 2; ++ks) {
                bf16x8 pf = *(const bf16x8*)&P_lds[w][lr][ks * 32 + lk * 8];
                bf16x8 vf = *(const bf16x8*)&Vt[cb * 16 + lr][ks * 32 + lk * 8];
                accy[cb] = __builtin_amdgcn_mfma_f32_16x16x32_bf16(pf, vf, accy[cb], 0, 0, 0);
            }
        }
    }

    // normalize + store y (fp32, [B,T,E] with heads interleaved)
#pragma unroll
    for (int cb = 0; cb < 4; ++cb) {
#pragma unroll
        for (int r = 0; r < 4; ++r) {
            const int tq = q0 + w * 16 + lk * 4 + r;
            y[(size_t)(b * T_ + tq) * E_ + nh * HS_ + cb * 16 + lr] =
                accy[cb][r] / l[r];
        }
    }
}

// ---------------------------------------------------------------------------
extern "C" void kernel_launch(void* const* d_in, const int* in_sizes, int n_in,
                              void* d_out, int out_size, void* d_ws, size_t ws_size,
                              hipStream_t stream)
{
    const float* x      = (const float*)d_in[0];
    const float* W_attn = (const float*)d_in[1];
    const float* b_attn = (const float*)d_in[2];
    const float* W_proj = (const float*)d_in[3];
    const float* b_proj = (const float*)d_in[4];
    float* out = (float*)d_out;

    unsigned short* qkv_ws = (unsigned short*)d_ws;                 // bf16 [8192, 2304]
    const size_t qkv_bytes = (size_t)B_ * T_ * QKV_ROW * sizeof(unsigned short);
    float* y_ws = (float*)((char*)d_ws + qkv_bytes);                // fp32 [8192, 768]

    dim3 blk(256);

    // 1) qkv = x @ W_attn + b_attn   (M=8192, N=2304, K=768) -> bf16
    gemm_bias_kernel<true><<<dim3(QKV_ROW / 128, (B_ * T_) / 128), blk, 0, stream>>>(
        x, W_attn, b_attn, (void*)qkv_ws, B_ * T_, QKV_ROW, E_);

    // 2) causal flash attention -> y fp32
    flash_kernel<<<dim3(T_ / 64, B_ * NH_), blk, 0, stream>>>(qkv_ws, y_ws);

    // 3) out = y @ W_proj + b_proj   (M=8192, N=768, K=768) -> fp32
    gemm_bias_kernel<false><<<dim3(E_ / 128, (B_ * T_) / 128), blk, 0, stream>>>(
        y_ws, W_proj, b_proj, (void*)out, B_ * T_, E_, E_);
}

// Round 2
// 478.947 us; speedup vs baseline: 1.2323x; 1.2323x over previous
//
#include <hip/hip_runtime.h>
#include <hip/hip_bf16.h>
#include <cmath>

#define B_   2
#define T_   4096
#define E_   768
#define NH_  12
#define HS_  64
#define QKV_ROW (3 * E_)   // 2304

typedef __attribute__((ext_vector_type(8))) short bf16x8;
typedef __attribute__((ext_vector_type(4))) float f32x4;

__device__ __forceinline__ unsigned short f2bf(float f) {
    unsigned int u = __builtin_bit_cast(unsigned int, f);
    u = (u + 0x7FFFu + ((u >> 16) & 1u)) >> 16;
    return (unsigned short)u;
}

// ---------------------------------------------------------------------------
// GEMM: C[M,N] = A[M,K] (fp32) @ B[K,N] (fp32) + bias[N]
// 128x128 block tile, 4 waves (2x2), each wave 64x64 via 4x4 mfma 16x16x32 bf16
// ---------------------------------------------------------------------------
template<bool OUT_BF16>
__global__ __launch_bounds__(256) void gemm_bias_kernel(
    const float* __restrict__ A, const float* __restrict__ Bm,
    const float* __restrict__ bias, void* __restrict__ Cout,
    int M, int N, int K)
{
    __shared__ __align__(16) unsigned short As[128][40];  // [m][k] pad->80B rows
    __shared__ __align__(16) unsigned short Bt[128][40];  // [n][k] (B transposed)

    const int tid  = threadIdx.x;
    const int m0   = blockIdx.y * 128;
    const int n0   = blockIdx.x * 128;
    const int w    = tid >> 6;
    const int lane = tid & 63;
    const int lr   = lane & 15;
    const int lk   = lane >> 4;
    const int wm   = (w >> 1) * 64;
    const int wn   = (w & 1) * 64;

    f32x4 acc[4][4];
#pragma unroll
    for (int i = 0; i < 4; ++i)
#pragma unroll
        for (int j = 0; j < 4; ++j) acc[i][j] = (f32x4){0.f, 0.f, 0.f, 0.f};

    const int ar = tid >> 3;         // 0..31 (A row group)
    const int ak = (tid & 7) * 4;    // 0..28 (A k col)
    const int bn = (tid & 31) * 4;   // 0..124 (B n col)
    const int bk = tid >> 5;         // 0..7  (B k row group)

    for (int k0 = 0; k0 < K; k0 += 32) {
        // stage A tile 128x32 (fp32 -> bf16)
#pragma unroll
        for (int i = 0; i < 4; ++i) {
            const int row = ar + i * 32;
            const float4 v = *(const float4*)&A[(size_t)(m0 + row) * K + k0 + ak];
            ushort4 s;
            s.x = f2bf(v.x); s.y = f2bf(v.y); s.z = f2bf(v.z); s.w = f2bf(v.w);
            *(ushort4*)&As[row][ak] = s;
        }
        // stage B tile 32x128 transposed -> Bt[n][k]
#pragma unroll
        for (int i = 0; i < 4; ++i) {
            const int k = bk + i * 8;
            const float4 v = *(const float4*)&Bm[(size_t)(k0 + k) * N + n0 + bn];
            Bt[bn + 0][k] = f2bf(v.x);
            Bt[bn + 1][k] = f2bf(v.y);
            Bt[bn + 2][k] = f2bf(v.z);
            Bt[bn + 3][k] = f2bf(v.w);
        }
        __syncthreads();

        bf16x8 a[4], b[4];
#pragma unroll
        for (int i = 0; i < 4; ++i)
            a[i] = *(const bf16x8*)&As[wm + i * 16 + lr][lk * 8];
#pragma unroll
        for (int j = 0; j < 4; ++j)
            b[j] = *(const bf16x8*)&Bt[wn + j * 16 + lr][lk * 8];
#pragma unroll
        for (int i = 0; i < 4; ++i)
#pragma unroll
            for (int j = 0; j < 4; ++j)
                acc[i][j] = __builtin_amdgcn_mfma_f32_16x16x32_bf16(
                    a[i], b[j], acc[i][j], 0, 0, 0);
        __syncthreads();
    }

    // epilogue: C/D layout col = lane&15, row = (lane>>4)*4 + reg
#pragma unroll
    for (int i = 0; i < 4; ++i) {
#pragma unroll
        for (int j = 0; j < 4; ++j) {
#pragma unroll
            for (int r = 0; r < 4; ++r) {
                const int row = m0 + wm + i * 16 + lk * 4 + r;
                const int col = n0 + wn + j * 16 + lr;
                const float v = acc[i][j][r] + bias[col];
                if (OUT_BF16)
                    ((unsigned short*)Cout)[(size_t)row * N + col] = f2bf(v);
                else
                    ((float*)Cout)[(size_t)row * N + col] = v;
            }
        }
    }
}

// ---------------------------------------------------------------------------
// Flash attention (causal), work-balanced: block qp handles q-tiles qp and
// 63-qp (combined cost 65 kv-tiles for every block). One K/V staging serves
// both q-tiles. 4 waves x 16 q-rows per q-tile. qkv bf16 [B, T, 3, NH, HS].
// ---------------------------------------------------------------------------
__global__ __launch_bounds__(256) void flash_kernel(
    const unsigned short* __restrict__ qkv, float* __restrict__ y)
{
    __shared__ __align__(16) unsigned short K_lds[64][72];     // [kv][hs]
    __shared__ __align__(16) unsigned short Vt[64][72];        // [hs][kv]
    __shared__ __align__(16) unsigned short P_lds[4][16][72];  // per-wave P

    const int tid  = threadIdx.x;
    const int w    = tid >> 6;
    const int lane = tid & 63;
    const int lr   = lane & 15;
    const int lk   = lane >> 4;
    const int head = blockIdx.y;
    const int b    = head / NH_;
    const int nh   = head % NH_;
    const int qb_lo = blockIdx.x;        // 0..31
    const int qb_hi = 63 - qb_lo;        // 32..63
    const int q0_lo = qb_lo * 64;
    const int q0_hi = qb_hi * 64;

    const unsigned short* qkv_b = qkv + (size_t)b * T_ * QKV_ROW;

    // Q fragments (A-layout: row = lane&15, k = (lane>>4)*8 + j)
    bf16x8 qf_lo[2], qf_hi[2];
    {
        const unsigned short* qrl =
            qkv_b + (size_t)(q0_lo + w * 16 + lr) * QKV_ROW + nh * HS_;
        qf_lo[0] = *(const bf16x8*)(qrl + lk * 8);
        qf_lo[1] = *(const bf16x8*)(qrl + 32 + lk * 8);
        const unsigned short* qrh =
            qkv_b + (size_t)(q0_hi + w * 16 + lr) * QKV_ROW + nh * HS_;
        qf_hi[0] = *(const bf16x8*)(qrh + lk * 8);
        qf_hi[1] = *(const bf16x8*)(qrh + 32 + lk * 8);
    }

    f32x4 acc_lo[4], acc_hi[4];
    float m_lo[4], l_lo[4], m_hi[4], l_hi[4];
#pragma unroll
    for (int i = 0; i < 4; ++i) {
        acc_lo[i] = (f32x4){0.f, 0.f, 0.f, 0.f};
        acc_hi[i] = (f32x4){0.f, 0.f, 0.f, 0.f};
    }
#pragma unroll
    for (int r = 0; r < 4; ++r) {
        m_lo[r] = -INFINITY; l_lo[r] = 0.f;
        m_hi[r] = -INFINITY; l_hi[r] = 0.f;
    }

    const int sr = tid >> 2;          // 0..63 staging row (kv)
    const int sc = (tid & 3) * 16;    // staging col base (hs)

    // process one kv-tile for one q-tile (reads K_lds/Vt, uses P_lds[w])
    auto process = [&](const bf16x8* qf, f32x4* accy, float* m, float* l,
                       int q0, int kv0, bool diag) {
        f32x4 s[4];
#pragma unroll
        for (int cb = 0; cb < 4; ++cb) {
            s[cb] = (f32x4){0.f, 0.f, 0.f, 0.f};
#pragma unroll
            for (int ks = 0; ks < 2; ++ks) {
                bf16x8 kf = *(const bf16x8*)&K_lds[cb * 16 + lr][ks * 32 + lk * 8];
                s[cb] = __builtin_amdgcn_mfma_f32_16x16x32_bf16(qf[ks], kf, s[cb], 0, 0, 0);
            }
        }
        const float scale = 0.125f;  // 1/sqrt(64)
        if (diag) {
#pragma unroll
            for (int cb = 0; cb < 4; ++cb) {
                const int tk = kv0 + cb * 16 + lr;
#pragma unroll
                for (int r = 0; r < 4; ++r) {
                    const int tq = q0 + w * 16 + lk * 4 + r;
                    const float v = s[cb][r] * scale;
                    s[cb][r] = (tk <= tq) ? v : -INFINITY;
                }
            }
        } else {
#pragma unroll
            for (int cb = 0; cb < 4; ++cb)
#pragma unroll
                for (int r = 0; r < 4; ++r) s[cb][r] *= scale;
        }

        // online softmax: row (lk,r) spread across 16 lanes (lr) -> shfl_xor
        float p[4][4];
#pragma unroll
        for (int r = 0; r < 4; ++r) {
            float mx = fmaxf(fmaxf(s[0][r], s[1][r]), fmaxf(s[2][r], s[3][r]));
            mx = fmaxf(mx, __shfl_xor(mx, 1));
            mx = fmaxf(mx, __shfl_xor(mx, 2));
            mx = fmaxf(mx, __shfl_xor(mx, 4));
            mx = fmaxf(mx, __shfl_xor(mx, 8));
            const float mnew  = fmaxf(m[r], mx);
            const float alpha = __expf(m[r] - mnew);
            m[r] = mnew;
            float rs = 0.f;
#pragma unroll
            for (int cb = 0; cb < 4; ++cb) {
                const float pv = __expf(s[cb][r] - mnew);
                p[cb][r] = pv;
                rs += pv;
            }
            rs += __shfl_xor(rs, 1);
            rs += __shfl_xor(rs, 2);
            rs += __shfl_xor(rs, 4);
            rs += __shfl_xor(rs, 8);
            l[r] = l[r] * alpha + rs;
#pragma unroll
            for (int cb = 0; cb < 4; ++cb) accy[cb][r] *= alpha;
        }

        // P (C-layout) -> per-wave LDS (same-wave dep; no barrier needed)
#pragma unroll
        for (int cb = 0; cb < 4; ++cb)
#pragma unroll
            for (int r = 0; r < 4; ++r)
                P_lds[w][lk * 4 + r][cb * 16 + lr] = f2bf(p[cb][r]);

        // Y += P @ V
#pragma unroll
        for (int cb = 0; cb < 4; ++cb) {
#pragma unroll
            for (int ks = 0; ks < 2; ++ks) {
                bf16x8 pf = *(const bf16x8*)&P_lds[w][lr][ks * 32 + lk * 8];
                bf16x8 vf = *(const bf16x8*)&Vt[cb * 16 + lr][ks * 32 + lk * 8];
                accy[cb] = __builtin_amdgcn_mfma_f32_16x16x32_bf16(pf, vf, accy[cb], 0, 0, 0);
            }
        }
    };

    for (int j = 0; j <= qb_hi; ++j) {
        const int kv0 = j * 64;
        __syncthreads();  // prior tile's reads of K_lds/Vt complete
        {
            const unsigned short* krow =
                qkv_b + (size_t)(kv0 + sr) * QKV_ROW + E_ + nh * HS_ + sc;
            const unsigned short* vrow = krow + E_;
            int4 k01 = *(const int4*)krow;
            int4 k23 = *(const int4*)(krow + 8);
            *(int4*)&K_lds[sr][sc]     = k01;
            *(int4*)&K_lds[sr][sc + 8] = k23;
            int4 v01 = *(const int4*)vrow;
            int4 v23 = *(const int4*)(vrow + 8);
            const unsigned short* vs0 = (const unsigned short*)&v01;
            const unsigned short* vs1 = (const unsigned short*)&v23;
#pragma unroll
            for (int i = 0; i < 8; ++i) Vt[sc + i][sr] = vs0[i];
#pragma unroll
            for (int i = 0; i < 8; ++i) Vt[sc + 8 + i][sr] = vs1[i];
        }
        __syncthreads();

        process(qf_hi, acc_hi, m_hi, l_hi, q0_hi, kv0, j == qb_hi);
        if (j <= qb_lo)
            process(qf_lo, acc_lo, m_lo, l_lo, q0_lo, kv0, j == qb_lo);
    }

    // normalize + store y (fp32, [B,T,E] heads interleaved)
#pragma unroll
    for (int cb = 0; cb < 4; ++cb) {
#pragma unroll
        for (int r = 0; r < 4; ++r) {
            const int tq_h = q0_hi + w * 16 + lk * 4 + r;
            y[(size_t)(b * T_ + tq_h) * E_ + nh * HS_ + cb * 16 + lr] =
                acc_hi[cb][r] / l_hi[r];
            const int tq_l = q0_lo + w * 16 + lk * 4 + r;
            y[(size_t)(b * T_ + tq_l) * E_ + nh * HS_ + cb * 16 + lr] =
                acc_lo[cb][r] / l_lo[r];
        }
    }
}

// ---------------------------------------------------------------------------
extern "C" void kernel_launch(void* const* d_in, const int* in_sizes, int n_in,
                              void* d_out, int out_size, void* d_ws, size_t ws_size,
                              hipStream_t stream)
{
    const float* x      = (const float*)d_in[0];
    const float* W_attn = (const float*)d_in[1];
    const float* b_attn = (const float*)d_in[2];
    const float* W_proj = (const float*)d_in[3];
    const float* b_proj = (const float*)d_in[4];
    float* out = (float*)d_out;

    unsigned short* qkv_ws = (unsigned short*)d_ws;                 // bf16 [8192, 2304]
    const size_t qkv_bytes = (size_t)B_ * T_ * QKV_ROW * sizeof(unsigned short);
    float* y_ws = (float*)((char*)d_ws + qkv_bytes);                // fp32 [8192, 768]

    dim3 blk(256);

    // 1) qkv = x @ W_attn + b_attn   (M=8192, N=2304, K=768) -> bf16
    gemm_bias_kernel<true><<<dim3(QKV_ROW / 128, (B_ * T_) / 128), blk, 0, stream>>>(
        x, W_attn, b_attn, (void*)qkv_ws, B_ * T_, QKV_ROW, E_);

    // 2) causal flash attention (work-balanced pairing) -> y fp32
    flash_kernel<<<dim3(T_ / 128, B_ * NH_), blk, 0, stream>>>(qkv_ws, y_ws);

    // 3) out = y @ W_proj + b_proj   (M=8192, N=768, K=768) -> fp32
    gemm_bias_kernel<false><<<dim3(E_ / 128, (B_ * T_) / 128), blk, 0, stream>>>(
        y_ws, W_proj, b_proj, (void*)out, B_ * T_, E_, E_);
}

// Round 4
// 458.817 us; speedup vs baseline: 1.2863x; 1.0439x over previous
//
#include <hip/hip_runtime.h>
#include <hip/hip_bf16.h>
#include <cmath>

#define B_   2
#define T_   4096
#define E_   768
#define NH_  12
#define HS_  64
#define QKV_ROW (3 * E_)   // 2304

typedef __attribute__((ext_vector_type(8))) short bf16x8;
typedef __attribute__((ext_vector_type(4))) float f32x4;

__device__ __forceinline__ unsigned short f2bf(float f) {
    unsigned int u = __builtin_bit_cast(unsigned int, f);
    u = (u + 0x7FFFu + ((u >> 16) & 1u)) >> 16;
    return (unsigned short)u;
}

// ---------------------------------------------------------------------------
// GEMM: C[M,N] = A[M,K] (fp32) @ B[K,N] (fp32) + bias[N]
// 128x128 block tile, 4 waves (2x2), each wave 64x64 via 4x4 mfma 16x16x32 bf16
// ---------------------------------------------------------------------------
template<bool OUT_BF16>
__global__ __launch_bounds__(256) void gemm_bias_kernel(
    const float* __restrict__ A, const float* __restrict__ Bm,
    const float* __restrict__ bias, void* __restrict__ Cout,
    int M, int N, int K)
{
    __shared__ __align__(16) unsigned short As[128][40];  // [m][k] pad->80B rows
    __shared__ __align__(16) unsigned short Bt[128][40];  // [n][k] (B transposed)

    const int tid  = threadIdx.x;
    const int m0   = blockIdx.y * 128;
    const int n0   = blockIdx.x * 128;
    const int w    = tid >> 6;
    const int lane = tid & 63;
    const int lr   = lane & 15;
    const int lk   = lane >> 4;
    const int wm   = (w >> 1) * 64;
    const int wn   = (w & 1) * 64;

    f32x4 acc[4][4];
#pragma unroll
    for (int i = 0; i < 4; ++i)
#pragma unroll
        for (int j = 0; j < 4; ++j) acc[i][j] = (f32x4){0.f, 0.f, 0.f, 0.f};

    const int ar = tid >> 3;         // 0..31 (A row group)
    const int ak = (tid & 7) * 4;    // 0..28 (A k col)
    const int bn = (tid & 31) * 4;   // 0..124 (B n col)
    const int bk = tid >> 5;         // 0..7  (B k row group)

    for (int k0 = 0; k0 < K; k0 += 32) {
#pragma unroll
        for (int i = 0; i < 4; ++i) {
            const int row = ar + i * 32;
            const float4 v = *(const float4*)&A[(size_t)(m0 + row) * K + k0 + ak];
            ushort4 s;
            s.x = f2bf(v.x); s.y = f2bf(v.y); s.z = f2bf(v.z); s.w = f2bf(v.w);
            *(ushort4*)&As[row][ak] = s;
        }
#pragma unroll
        for (int i = 0; i < 4; ++i) {
            const int k = bk + i * 8;
            const float4 v = *(const float4*)&Bm[(size_t)(k0 + k) * N + n0 + bn];
            Bt[bn + 0][k] = f2bf(v.x);
            Bt[bn + 1][k] = f2bf(v.y);
            Bt[bn + 2][k] = f2bf(v.z);
            Bt[bn + 3][k] = f2bf(v.w);
        }
        __syncthreads();

        bf16x8 a[4], b[4];
#pragma unroll
        for (int i = 0; i < 4; ++i)
            a[i] = *(const bf16x8*)&As[wm + i * 16 + lr][lk * 8];
#pragma unroll
        for (int j = 0; j < 4; ++j)
            b[j] = *(const bf16x8*)&Bt[wn + j * 16 + lr][lk * 8];
#pragma unroll
        for (int i = 0; i < 4; ++i)
#pragma unroll
            for (int j = 0; j < 4; ++j)
                acc[i][j] = __builtin_amdgcn_mfma_f32_16x16x32_bf16(
                    a[i], b[j], acc[i][j], 0, 0, 0);
        __syncthreads();
    }

#pragma unroll
    for (int i = 0; i < 4; ++i) {
#pragma unroll
        for (int j = 0; j < 4; ++j) {
#pragma unroll
            for (int r = 0; r < 4; ++r) {
                const int row = m0 + wm + i * 16 + lk * 4 + r;
                const int col = n0 + wn + j * 16 + lr;
                const float v = acc[i][j][r] + bias[col];
                if (OUT_BF16)
                    ((unsigned short*)Cout)[(size_t)row * N + col] = f2bf(v);
                else
                    ((float*)Cout)[(size_t)row * N + col] = v;
            }
        }
    }
}

// ---------------------------------------------------------------------------
// Flash attention (causal), work-balanced pairing + swapped-operand MFMA.
// Block qp handles q-tiles qp and 63-qp. S^T = mfma(K,Q): each lane owns one
// q-row (q = lane&15), 16 kv values -> in-lane softmax + 2 shuffles.
// Y^T = mfma(V^T, P^T). qkv bf16 [B, T, 3, NH, HS]; y fp32 [B, T, E].
// ---------------------------------------------------------------------------
__global__ __launch_bounds__(256) void flash_kernel(
    const unsigned short* __restrict__ qkv, float* __restrict__ y)
{
    __shared__ __align__(16) unsigned short K_lds[64][72];       // [kv][hs]
    __shared__ __align__(16) unsigned short Vt[64][72];          // [hs][kv] chunk-swizzled
    __shared__ __align__(16) unsigned short Pt[4][2][16][72];    // [wave][hi/lo][q][kv]

    const int tid  = threadIdx.x;
    const int w    = tid >> 6;
    const int lane = tid & 63;
    const int lr   = lane & 15;
    const int lk   = lane >> 4;
    const int head = blockIdx.y;
    const int b    = head / NH_;
    const int nh   = head % NH_;
    const int qb_lo = blockIdx.x;        // 0..31
    const int qb_hi = 63 - qb_lo;        // 32..63
    const int q0_lo = qb_lo * 64;
    const int q0_hi = qb_hi * 64;

    const unsigned short* qkv_b = qkv + (size_t)b * T_ * QKV_ROW;

    // Q fragments: lane holds Q[q0 + w*16 + lr][ks*32 + lk*8 + j]
    bf16x8 qf_lo[2], qf_hi[2];
    {
        const unsigned short* qrl =
            qkv_b + (size_t)(q0_lo + w * 16 + lr) * QKV_ROW + nh * HS_;
        qf_lo[0] = *(const bf16x8*)(qrl + lk * 8);
        qf_lo[1] = *(const bf16x8*)(qrl + 32 + lk * 8);
        const unsigned short* qrh =
            qkv_b + (size_t)(q0_hi + w * 16 + lr) * QKV_ROW + nh * HS_;
        qf_hi[0] = *(const bf16x8*)(qrh + lk * 8);
        qf_hi[1] = *(const bf16x8*)(qrh + 32 + lk * 8);
    }

    // acc[cb2][r]: hs = cb2*16 + lk*4 + r, q = lr  (Y^T layout)
    f32x4 acc_lo[4], acc_hi[4];
#pragma unroll
    for (int i = 0; i < 4; ++i) {
        acc_lo[i] = (f32x4){0.f, 0.f, 0.f, 0.f};
        acc_hi[i] = (f32x4){0.f, 0.f, 0.f, 0.f};
    }
    float m_lo = -INFINITY, l_lo = 0.f, m_hi = -INFINITY, l_hi = 0.f;

    const int sr = tid >> 2;          // 0..63 staging row (kv)
    const int sc = (tid & 3) * 16;    // staging col base (hs)

    const float beta = 0.18033688011f;  // (1/sqrt(64)) * log2(e)

    // softmax on S^T fragments + pack P^T into Pt[w][which]
    auto softmax_store = [&](f32x4* st, f32x4* acc, float& m, float& l,
                             int q0, int kv0, bool diag,
                             unsigned short (*PtW)[72]) {
        float sv[4][4];
        float mx = -INFINITY;
        const int tq = q0 + w * 16 + lr;
#pragma unroll
        for (int cb = 0; cb < 4; ++cb) {
#pragma unroll
            for (int r = 0; r < 4; ++r) {
                float v = st[cb][r] * beta;
                if (diag) {
                    const int tk = kv0 + cb * 16 + lk * 4 + r;
                    if (tk > tq) v = -INFINITY;
                }
                sv[cb][r] = v;
                mx = fmaxf(mx, v);
            }
        }
        mx = fmaxf(mx, __shfl_xor(mx, 16));
        mx = fmaxf(mx, __shfl_xor(mx, 32));
        const float mnew  = fmaxf(m, mx);
        const float alpha = exp2f(m - mnew);
        m = mnew;
        float rs = 0.f;
        ushort4 pk[4];
#pragma unroll
        for (int cb = 0; cb < 4; ++cb) {
            float pv[4];
#pragma unroll
            for (int r = 0; r < 4; ++r) {
                pv[r] = exp2f(sv[cb][r] - mnew);
                rs += pv[r];
            }
            pk[cb].x = f2bf(pv[0]); pk[cb].y = f2bf(pv[1]);
            pk[cb].z = f2bf(pv[2]); pk[cb].w = f2bf(pv[3]);
        }
        rs += __shfl_xor(rs, 16);
        rs += __shfl_xor(rs, 32);
        l = l * alpha + rs;
#pragma unroll
        for (int cb2 = 0; cb2 < 4; ++cb2) acc[cb2] *= alpha;
        // P^T[kv][q] stored as Pt[q][kv]: lane writes kv = cb*16+lk*4..+3
#pragma unroll
        for (int cb = 0; cb < 4; ++cb)
            *(ushort4*)&PtW[lr][cb * 16 + lk * 4] = pk[cb];
    };

    for (int j = 0; j <= qb_hi; ++j) {
        const int kv0 = j * 64;
        const bool do_lo = (j <= qb_lo);
        __syncthreads();  // prior tile's K_lds/Vt reads complete
        {
            const unsigned short* krow =
                qkv_b + (size_t)(kv0 + sr) * QKV_ROW + E_ + nh * HS_ + sc;
            const unsigned short* vrow = krow + E_;
            int4 k01 = *(const int4*)krow;
            int4 k23 = *(const int4*)(krow + 8);
            *(int4*)&K_lds[sr][sc]     = k01;
            *(int4*)&K_lds[sr][sc + 8] = k23;
            int4 v01 = *(const int4*)vrow;
            int4 v23 = *(const int4*)(vrow + 8);
            const unsigned short* vs0 = (const unsigned short*)&v01;
            const unsigned short* vs1 = (const unsigned short*)&v23;
            // V^T[h][kv] at Vt[h][((kv>>3)^(h>>3))*8 + (kv&7)] (bank swizzle)
            const int kvhi = sr >> 3, kvlo = sr & 7;
#pragma unroll
            for (int i = 0; i < 8; ++i) {
                const int h = sc + i;
                Vt[h][((kvhi ^ (h >> 3)) << 3) + kvlo] = vs0[i];
            }
#pragma unroll
            for (int i = 0; i < 8; ++i) {
                const int h = sc + 8 + i;
                Vt[h][((kvhi ^ (h >> 3)) << 3) + kvlo] = vs1[i];
            }
        }
        __syncthreads();

        // K fragments (shared by both q-tiles)
        bf16x8 kf[4][2];
#pragma unroll
        for (int cb = 0; cb < 4; ++cb)
#pragma unroll
            for (int ks = 0; ks < 2; ++ks)
                kf[cb][ks] = *(const bf16x8*)&K_lds[cb * 16 + lr][ks * 32 + lk * 8];

        // S^T = K @ Q^T : row = kv (cb*16+lk*4+r), col = q (lr)
        f32x4 st_hi[4], st_lo[4];
        __builtin_amdgcn_s_setprio(1);
#pragma unroll
        for (int cb = 0; cb < 4; ++cb) {
            st_hi[cb] = (f32x4){0.f, 0.f, 0.f, 0.f};
            st_hi[cb] = __builtin_amdgcn_mfma_f32_16x16x32_bf16(kf[cb][0], qf_hi[0], st_hi[cb], 0, 0, 0);
            st_hi[cb] = __builtin_amdgcn_mfma_f32_16x16x32_bf16(kf[cb][1], qf_hi[1], st_hi[cb], 0, 0, 0);
        }
        if (do_lo) {
#pragma unroll
            for (int cb = 0; cb < 4; ++cb) {
                st_lo[cb] = (f32x4){0.f, 0.f, 0.f, 0.f};
                st_lo[cb] = __builtin_amdgcn_mfma_f32_16x16x32_bf16(kf[cb][0], qf_lo[0], st_lo[cb], 0, 0, 0);
                st_lo[cb] = __builtin_amdgcn_mfma_f32_16x16x32_bf16(kf[cb][1], qf_lo[1], st_lo[cb], 0, 0, 0);
            }
        }
        __builtin_amdgcn_s_setprio(0);

        softmax_store(st_hi, acc_hi, m_hi, l_hi, q0_hi, kv0, j == qb_hi, Pt[w][0]);
        if (do_lo)
            softmax_store(st_lo, acc_lo, m_lo, l_lo, q0_lo, kv0, j == qb_lo, Pt[w][1]);

        // V^T fragments (shared) + P^T fragments
        bf16x8 vf[4][2];
#pragma unroll
        for (int cb2 = 0; cb2 < 4; ++cb2) {
            const int row = cb2 * 16 + lr;
            const int sw  = row >> 3;
#pragma unroll
            for (int ks = 0; ks < 2; ++ks)
                vf[cb2][ks] = *(const bf16x8*)&Vt[row][(((ks * 4 + lk) ^ sw) << 3)];
        }
        bf16x8 pf_hi[2], pf_lo[2];
#pragma unroll
        for (int ks = 0; ks < 2; ++ks)
            pf_hi[ks] = *(const bf16x8*)&Pt[w][0][lr][ks * 32 + lk * 8];
        if (do_lo) {
#pragma unroll
            for (int ks = 0; ks < 2; ++ks)
                pf_lo[ks] = *(const bf16x8*)&Pt[w][1][lr][ks * 32 + lk * 8];
        }

        // Y^T += V^T @ P^T : row = hs (cb2*16+lk*4+r), col = q (lr)
        __builtin_amdgcn_s_setprio(1);
#pragma unroll
        for (int cb2 = 0; cb2 < 4; ++cb2) {
            acc_hi[cb2] = __builtin_amdgcn_mfma_f32_16x16x32_bf16(vf[cb2][0], pf_hi[0], acc_hi[cb2], 0, 0, 0);
            acc_hi[cb2] = __builtin_amdgcn_mfma_f32_16x16x32_bf16(vf[cb2][1], pf_hi[1], acc_hi[cb2], 0, 0, 0);
        }
        if (do_lo) {
#pragma unroll
            for (int cb2 = 0; cb2 < 4; ++cb2) {
                acc_lo[cb2] = __builtin_amdgcn_mfma_f32_16x16x32_bf16(vf[cb2][0], pf_lo[0], acc_lo[cb2], 0, 0, 0);
                acc_lo[cb2] = __builtin_amdgcn_mfma_f32_16x16x32_bf16(vf[cb2][1], pf_lo[1], acc_lo[cb2], 0, 0, 0);
            }
        }
        __builtin_amdgcn_s_setprio(0);
    }

    // normalize + store y: 4 float4 stores per q-tile
    {
        const float li_hi = 1.0f / l_hi;
        const float li_lo = 1.0f / l_lo;
        const int tq_hi = q0_hi + w * 16 + lr;
        const int tq_lo = q0_lo + w * 16 + lr;
        float* yh = &y[(size_t)(b * T_ + tq_hi) * E_ + nh * HS_];
        float* yl = &y[(size_t)(b * T_ + tq_lo) * E_ + nh * HS_];
#pragma unroll
        for (int cb2 = 0; cb2 < 4; ++cb2) {
            float4 oh, ol;
            oh.x = acc_hi[cb2][0] * li_hi; oh.y = acc_hi[cb2][1] * li_hi;
            oh.z = acc_hi[cb2][2] * li_hi; oh.w = acc_hi[cb2][3] * li_hi;
            ol.x = acc_lo[cb2][0] * li_lo; ol.y = acc_lo[cb2][1] * li_lo;
            ol.z = acc_lo[cb2][2] * li_lo; ol.w = acc_lo[cb2][3] * li_lo;
            *(float4*)&yh[cb2 * 16 + lk * 4] = oh;
            *(float4*)&yl[cb2 * 16 + lk * 4] = ol;
        }
    }
}

// ---------------------------------------------------------------------------
extern "C" void kernel_launch(void* const* d_in, const int* in_sizes, int n_in,
                              void* d_out, int out_size, void* d_ws, size_t ws_size,
                              hipStream_t stream)
{
    const float* x      = (const float*)d_in[0];
    const float* W_attn = (const float*)d_in[1];
    const float* b_attn = (const float*)d_in[2];
    const float* W_proj = (const float*)d_in[3];
    const float* b_proj = (const float*)d_in[4];
    float* out = (float*)d_out;

    unsigned short* qkv_ws = (unsigned short*)d_ws;                 // bf16 [8192, 2304]
    const size_t qkv_bytes = (size_t)B_ * T_ * QKV_ROW * sizeof(unsigned short);
    float* y_ws = (float*)((char*)d_ws + qkv_bytes);                // fp32 [8192, 768]

    dim3 blk(256);

    // 1) qkv = x @ W_attn + b_attn   (M=8192, N=2304, K=768) -> bf16
    gemm_bias_kernel<true><<<dim3(QKV_ROW / 128, (B_ * T_) / 128), blk, 0, stream>>>(
        x, W_attn, b_attn, (void*)qkv_ws, B_ * T_, QKV_ROW, E_);

    // 2) causal flash attention (paired + swapped-operand) -> y fp32
    flash_kernel<<<dim3(T_ / 128, B_ * NH_), blk, 0, stream>>>(qkv_ws, y_ws);

    // 3) out = y @ W_proj + b_proj   (M=8192, N=768, K=768) -> fp32
    gemm_bias_kernel<false><<<dim3(E_ / 128, (B_ * T_) / 128), blk, 0, stream>>>(
        y_ws, W_proj, b_proj, (void*)out, B_ * T_, E_, E_);
}

// Round 5
// 430.294 us; speedup vs baseline: 1.3716x; 1.0663x over previous
//
#include <hip/hip_runtime.h>
#include <hip/hip_bf16.h>
#include <cmath>

#define B_   2
#define T_   4096
#define E_   768
#define NH_  12
#define HS_  64
#define QKV_ROW (3 * E_)   // 2304
#define LSE_N (B_ * NH_ * T_)   // 98304
#define BTE   (B_ * T_ * E_)    // 6291456

typedef __attribute__((ext_vector_type(8))) short bf16x8;
typedef __attribute__((ext_vector_type(4))) float f32x4;

__device__ __forceinline__ unsigned short f2bf(float f) {
    unsigned int u = __builtin_bit_cast(unsigned int, f);
    u = (u + 0x7FFFu + ((u >> 16) & 1u)) >> 16;
    return (unsigned short)u;
}
__device__ __forceinline__ float bf2f(unsigned short s) {
    unsigned int u = (unsigned int)s << 16;
    return __builtin_bit_cast(float, u);
}

// ---------------------------------------------------------------------------
// GEMM: C[M,N] = A[M,K] @ B[K,N] + bias[N].  A fp32 or bf16 (lda-strided).
// 128x128 block tile, 4 waves (2x2), each wave 64x64 via 4x4 mfma 16x16x32 bf16
// ---------------------------------------------------------------------------
template<bool A_BF16, bool OUT_BF16>
__global__ __launch_bounds__(256) void gemm_bias_kernel(
    const void* __restrict__ Ain, const float* __restrict__ Bm,
    const float* __restrict__ bias, void* __restrict__ Cout,
    int M, int N, int K, int lda)
{
    __shared__ __align__(16) unsigned short As[128][40];  // [m][k]
    __shared__ __align__(16) unsigned short Bt[128][40];  // [n][k] (B transposed)

    const int tid  = threadIdx.x;
    const int m0   = blockIdx.y * 128;
    const int n0   = blockIdx.x * 128;
    const int w    = tid >> 6;
    const int lane = tid & 63;
    const int lr   = lane & 15;
    const int lk   = lane >> 4;
    const int wm   = (w >> 1) * 64;
    const int wn   = (w & 1) * 64;

    f32x4 acc[4][4];
#pragma unroll
    for (int i = 0; i < 4; ++i)
#pragma unroll
        for (int j = 0; j < 4; ++j) acc[i][j] = (f32x4){0.f, 0.f, 0.f, 0.f};

    const int ar = tid >> 3;         // 0..31 (A row group)
    const int ak = (tid & 7) * 4;    // 0..28 (A k col)
    const int bn = (tid & 31) * 4;   // 0..124 (B n col)
    const int bk = tid >> 5;         // 0..7  (B k row group)

    for (int k0 = 0; k0 < K; k0 += 32) {
#pragma unroll
        for (int i = 0; i < 4; ++i) {
            const int row = ar + i * 32;
            if (A_BF16) {
                const unsigned short* Ab = (const unsigned short*)Ain;
                *(ushort4*)&As[row][ak] =
                    *(const ushort4*)&Ab[(size_t)(m0 + row) * lda + k0 + ak];
            } else {
                const float* Af = (const float*)Ain;
                const float4 v = *(const float4*)&Af[(size_t)(m0 + row) * lda + k0 + ak];
                ushort4 s;
                s.x = f2bf(v.x); s.y = f2bf(v.y); s.z = f2bf(v.z); s.w = f2bf(v.w);
                *(ushort4*)&As[row][ak] = s;
            }
        }
#pragma unroll
        for (int i = 0; i < 4; ++i) {
            const int k = bk + i * 8;
            const float4 v = *(const float4*)&Bm[(size_t)(k0 + k) * N + n0 + bn];
            Bt[bn + 0][k] = f2bf(v.x);
            Bt[bn + 1][k] = f2bf(v.y);
            Bt[bn + 2][k] = f2bf(v.z);
            Bt[bn + 3][k] = f2bf(v.w);
        }
        __syncthreads();

        bf16x8 a[4], b[4];
#pragma unroll
        for (int i = 0; i < 4; ++i)
            a[i] = *(const bf16x8*)&As[wm + i * 16 + lr][lk * 8];
#pragma unroll
        for (int j = 0; j < 4; ++j)
            b[j] = *(const bf16x8*)&Bt[wn + j * 16 + lr][lk * 8];
#pragma unroll
        for (int i = 0; i < 4; ++i)
#pragma unroll
            for (int j = 0; j < 4; ++j)
                acc[i][j] = __builtin_amdgcn_mfma_f32_16x16x32_bf16(
                    a[i], b[j], acc[i][j], 0, 0, 0);
        __syncthreads();
    }

#pragma unroll
    for (int i = 0; i < 4; ++i) {
#pragma unroll
        for (int j = 0; j < 4; ++j) {
#pragma unroll
            for (int r = 0; r < 4; ++r) {
                const int row = m0 + wm + i * 16 + lk * 4 + r;
                const int col = n0 + wn + j * 16 + lr;
                const float v = acc[i][j][r] + bias[col];
                if (OUT_BF16)
                    ((unsigned short*)Cout)[(size_t)row * N + col] = f2bf(v);
                else
                    ((float*)Cout)[(size_t)row * N + col] = v;
            }
        }
    }
}

// ---------------------------------------------------------------------------
// Flash attention (causal), paired q-tiles + 2-way kv parity split (grid.z).
// Block (qp, head, z) handles q-tiles qp & 63-qp over kv-tiles j ≡ z (mod 2).
// Writes bf16 partials into d_out (y_part[z]) + base-2 LSE into ws.
// ---------------------------------------------------------------------------
__global__ __launch_bounds__(256) void flash_kernel(
    const unsigned short* __restrict__ qkv,
    unsigned short* __restrict__ y_part,  // [2][B*T][E] bf16 (aliases d_out)
    float* __restrict__ lse)              // [2][B*NH*T]
{
    __shared__ __align__(16) unsigned short K_lds[64][72];    // [kv][hs]
    __shared__ __align__(16) unsigned short Vt[64][72];       // [hs][kv] swizzled
    __shared__ __align__(16) unsigned short Pt[4][16][72];    // per-wave P^T

    const int tid  = threadIdx.x;
    const int w    = tid >> 6;
    const int lane = tid & 63;
    const int lr   = lane & 15;
    const int lk   = lane >> 4;
    const int head = blockIdx.y;
    const int z    = blockIdx.z;
    const int b    = head / NH_;
    const int nh   = head % NH_;
    const int qb_lo = blockIdx.x;        // 0..31
    const int qb_hi = 63 - qb_lo;        // 32..63
    const int q0_lo = qb_lo * 64;
    const int q0_hi = qb_hi * 64;

    const unsigned short* qkv_b = qkv + (size_t)b * T_ * QKV_ROW;

    bf16x8 qf_lo[2], qf_hi[2];
    {
        const unsigned short* qrl =
            qkv_b + (size_t)(q0_lo + w * 16 + lr) * QKV_ROW + nh * HS_;
        qf_lo[0] = *(const bf16x8*)(qrl + lk * 8);
        qf_lo[1] = *(const bf16x8*)(qrl + 32 + lk * 8);
        const unsigned short* qrh =
            qkv_b + (size_t)(q0_hi + w * 16 + lr) * QKV_ROW + nh * HS_;
        qf_hi[0] = *(const bf16x8*)(qrh + lk * 8);
        qf_hi[1] = *(const bf16x8*)(qrh + 32 + lk * 8);
    }

    // acc[cb2][r]: hs = cb2*16 + lk*4 + r, q = lr  (Y^T layout)
    f32x4 acc_lo[4], acc_hi[4];
#pragma unroll
    for (int i = 0; i < 4; ++i) {
        acc_lo[i] = (f32x4){0.f, 0.f, 0.f, 0.f};
        acc_hi[i] = (f32x4){0.f, 0.f, 0.f, 0.f};
    }
    float m_lo = -INFINITY, l_lo = 0.f, m_hi = -INFINITY, l_hi = 0.f;

    const int sr = tid >> 2;          // staging row (kv)
    const int sc = (tid & 3) * 16;    // staging col base (hs)

    const float beta = 0.18033688011f;  // (1/sqrt(64)) * log2(e)

    auto softmax_store = [&](f32x4* st, f32x4* acc, float& m, float& l,
                             int q0, int kv0, bool diag,
                             unsigned short (*PtW)[72]) {
        float sv[4][4];
        float mx = -INFINITY;
        const int tq = q0 + w * 16 + lr;
#pragma unroll
        for (int cb = 0; cb < 4; ++cb) {
#pragma unroll
            for (int r = 0; r < 4; ++r) {
                float v = st[cb][r] * beta;
                if (diag) {
                    const int tk = kv0 + cb * 16 + lk * 4 + r;
                    if (tk > tq) v = -INFINITY;
                }
                sv[cb][r] = v;
                mx = fmaxf(mx, v);
            }
        }
        mx = fmaxf(mx, __shfl_xor(mx, 16));
        mx = fmaxf(mx, __shfl_xor(mx, 32));
        const float mnew  = fmaxf(m, mx);
        const float alpha = exp2f(m - mnew);
        m = mnew;
        float rs = 0.f;
        ushort4 pk[4];
#pragma unroll
        for (int cb = 0; cb < 4; ++cb) {
            float pv[4];
#pragma unroll
            for (int r = 0; r < 4; ++r) {
                pv[r] = exp2f(sv[cb][r] - mnew);
                rs += pv[r];
            }
            pk[cb].x = f2bf(pv[0]); pk[cb].y = f2bf(pv[1]);
            pk[cb].z = f2bf(pv[2]); pk[cb].w = f2bf(pv[3]);
        }
        rs += __shfl_xor(rs, 16);
        rs += __shfl_xor(rs, 32);
        l = l * alpha + rs;
#pragma unroll
        for (int cb2 = 0; cb2 < 4; ++cb2) acc[cb2] *= alpha;
#pragma unroll
        for (int cb = 0; cb < 4; ++cb)
            *(ushort4*)&PtW[lr][cb * 16 + lk * 4] = pk[cb];
    };

    for (int j = z; j <= qb_hi; j += 2) {
        const int kv0 = j * 64;
        const bool do_lo = (j <= qb_lo);
        __syncthreads();
        {
            const unsigned short* krow =
                qkv_b + (size_t)(kv0 + sr) * QKV_ROW + E_ + nh * HS_ + sc;
            const unsigned short* vrow = krow + E_;
            int4 k01 = *(const int4*)krow;
            int4 k23 = *(const int4*)(krow + 8);
            *(int4*)&K_lds[sr][sc]     = k01;
            *(int4*)&K_lds[sr][sc + 8] = k23;
            int4 v01 = *(const int4*)vrow;
            int4 v23 = *(const int4*)(vrow + 8);
            const unsigned short* vs0 = (const unsigned short*)&v01;
            const unsigned short* vs1 = (const unsigned short*)&v23;
            const int kvhi = sr >> 3, kvlo = sr & 7;
#pragma unroll
            for (int i = 0; i < 8; ++i) {
                const int h = sc + i;
                Vt[h][((kvhi ^ (h >> 3)) << 3) + kvlo] = vs0[i];
            }
#pragma unroll
            for (int i = 0; i < 8; ++i) {
                const int h = sc + 8 + i;
                Vt[h][((kvhi ^ (h >> 3)) << 3) + kvlo] = vs1[i];
            }
        }
        __syncthreads();

        bf16x8 kf[4][2];
#pragma unroll
        for (int cb = 0; cb < 4; ++cb)
#pragma unroll
            for (int ks = 0; ks < 2; ++ks)
                kf[cb][ks] = *(const bf16x8*)&K_lds[cb * 16 + lr][ks * 32 + lk * 8];

        f32x4 st_hi[4], st_lo[4];
        __builtin_amdgcn_s_setprio(1);
#pragma unroll
        for (int cb = 0; cb < 4; ++cb) {
            st_hi[cb] = (f32x4){0.f, 0.f, 0.f, 0.f};
            st_hi[cb] = __builtin_amdgcn_mfma_f32_16x16x32_bf16(kf[cb][0], qf_hi[0], st_hi[cb], 0, 0, 0);
            st_hi[cb] = __builtin_amdgcn_mfma_f32_16x16x32_bf16(kf[cb][1], qf_hi[1], st_hi[cb], 0, 0, 0);
        }
        if (do_lo) {
#pragma unroll
            for (int cb = 0; cb < 4; ++cb) {
                st_lo[cb] = (f32x4){0.f, 0.f, 0.f, 0.f};
                st_lo[cb] = __builtin_amdgcn_mfma_f32_16x16x32_bf16(kf[cb][0], qf_lo[0], st_lo[cb], 0, 0, 0);
                st_lo[cb] = __builtin_amdgcn_mfma_f32_16x16x32_bf16(kf[cb][1], qf_lo[1], st_lo[cb], 0, 0, 0);
            }
        }
        __builtin_amdgcn_s_setprio(0);

        // --- hi tile: softmax + PV ---
        softmax_store(st_hi, acc_hi, m_hi, l_hi, q0_hi, kv0, j == qb_hi, Pt[w]);
        bf16x8 vf[4][2];
#pragma unroll
        for (int cb2 = 0; cb2 < 4; ++cb2) {
            const int row = cb2 * 16 + lr;
            const int sw  = row >> 3;
#pragma unroll
            for (int ks = 0; ks < 2; ++ks)
                vf[cb2][ks] = *(const bf16x8*)&Vt[row][(((ks * 4 + lk) ^ sw) << 3)];
        }
        bf16x8 pf[2];
#pragma unroll
        for (int ks = 0; ks < 2; ++ks)
            pf[ks] = *(const bf16x8*)&Pt[w][lr][ks * 32 + lk * 8];
        __builtin_amdgcn_s_setprio(1);
#pragma unroll
        for (int cb2 = 0; cb2 < 4; ++cb2) {
            acc_hi[cb2] = __builtin_amdgcn_mfma_f32_16x16x32_bf16(vf[cb2][0], pf[0], acc_hi[cb2], 0, 0, 0);
            acc_hi[cb2] = __builtin_amdgcn_mfma_f32_16x16x32_bf16(vf[cb2][1], pf[1], acc_hi[cb2], 0, 0, 0);
        }
        __builtin_amdgcn_s_setprio(0);

        // --- lo tile: softmax + PV (reuses Pt[w]; same-wave ordering) ---
        if (do_lo) {
            softmax_store(st_lo, acc_lo, m_lo, l_lo, q0_lo, kv0, j == qb_lo, Pt[w]);
#pragma unroll
            for (int ks = 0; ks < 2; ++ks)
                pf[ks] = *(const bf16x8*)&Pt[w][lr][ks * 32 + lk * 8];
            __builtin_amdgcn_s_setprio(1);
#pragma unroll
            for (int cb2 = 0; cb2 < 4; ++cb2) {
                acc_lo[cb2] = __builtin_amdgcn_mfma_f32_16x16x32_bf16(vf[cb2][0], pf[0], acc_lo[cb2], 0, 0, 0);
                acc_lo[cb2] = __builtin_amdgcn_mfma_f32_16x16x32_bf16(vf[cb2][1], pf[1], acc_lo[cb2], 0, 0, 0);
            }
            __builtin_amdgcn_s_setprio(0);
        }
    }

    // store bf16 partials (Y^T layout -> [row][e]) + LSE
    {
        unsigned short* yp = y_part + (size_t)z * BTE;
        const float li_hi = (l_hi > 0.f) ? 1.0f / l_hi : 0.f;
        const float li_lo = (l_lo > 0.f) ? 1.0f / l_lo : 0.f;
        const int tq_hi = q0_hi + w * 16 + lr;
        const int tq_lo = q0_lo + w * 16 + lr;
        unsigned short* yh = &yp[(size_t)(b * T_ + tq_hi) * E_ + nh * HS_];
        unsigned short* yl = &yp[(size_t)(b * T_ + tq_lo) * E_ + nh * HS_];
#pragma unroll
        for (int cb2 = 0; cb2 < 4; ++cb2) {
            ushort4 oh, ol;
            oh.x = f2bf(acc_hi[cb2][0] * li_hi); oh.y = f2bf(acc_hi[cb2][1] * li_hi);
            oh.z = f2bf(acc_hi[cb2][2] * li_hi); oh.w = f2bf(acc_hi[cb2][3] * li_hi);
            ol.x = f2bf(acc_lo[cb2][0] * li_lo); ol.y = f2bf(acc_lo[cb2][1] * li_lo);
            ol.z = f2bf(acc_lo[cb2][2] * li_lo); ol.w = f2bf(acc_lo[cb2][3] * li_lo);
            *(ushort4*)&yh[cb2 * 16 + lk * 4] = oh;
            *(ushort4*)&yl[cb2 * 16 + lk * 4] = ol;
        }
        if (lk == 0) {
            float* lz = lse + (size_t)z * LSE_N + (size_t)head * T_;
            lz[tq_hi] = (l_hi > 0.f) ? (m_hi + log2f(l_hi)) : -1e30f;
            lz[tq_lo] = (l_lo > 0.f) ? (m_lo + log2f(l_lo)) : -1e30f;
        }
    }
}

// ---------------------------------------------------------------------------
// Merge the two kv-split partials; write bf16 y into the (dead) Q-slots of qkv.
// ---------------------------------------------------------------------------
__global__ __launch_bounds__(256) void merge_kernel(
    const unsigned short* __restrict__ y_part,  // [2][B*T][E] bf16
    const float* __restrict__ lse,              // [2][B*NH*T]
    unsigned short* __restrict__ qkv)           // y -> qkv[row][0:768]
{
    const int i  = blockIdx.x * 256 + threadIdx.x;   // 8-elem group
    const int e0 = i * 8;
    const int row = e0 / E_;            // b*T + t
    const int e   = e0 - row * E_;
    const int nh  = e >> 6;
    const int lidx = ((row >> 12) * NH_ + nh) * T_ + (row & (T_ - 1));
    const float s0 = lse[lidx];
    const float s1 = lse[LSE_N + lidx];
    const float M  = fmaxf(s0, s1);
    float w0 = exp2f(s0 - M), w1 = exp2f(s1 - M);
    const float inv = 1.0f / (w0 + w1);
    w0 *= inv; w1 *= inv;
    bf16x8 p0 = *(const bf16x8*)&y_part[e0];
    bf16x8 p1 = *(const bf16x8*)&y_part[(size_t)BTE + e0];
    ushort4 oa, ob;
    unsigned short o[8];
#pragma unroll
    for (int jj = 0; jj < 8; ++jj)
        o[jj] = f2bf(w0 * bf2f((unsigned short)p0[jj]) +
                     w1 * bf2f((unsigned short)p1[jj]));
    oa.x = o[0]; oa.y = o[1]; oa.z = o[2]; oa.w = o[3];
    ob.x = o[4]; ob.y = o[5]; ob.z = o[6]; ob.w = o[7];
    unsigned short* dst = &qkv[(size_t)row * QKV_ROW + e];
    *(ushort4*)dst = oa;
    *(ushort4*)(dst + 4) = ob;
}

// ---------------------------------------------------------------------------
extern "C" void kernel_launch(void* const* d_in, const int* in_sizes, int n_in,
                              void* d_out, int out_size, void* d_ws, size_t ws_size,
                              hipStream_t stream)
{
    const float* x      = (const float*)d_in[0];
    const float* W_attn = (const float*)d_in[1];
    const float* b_attn = (const float*)d_in[2];
    const float* W_proj = (const float*)d_in[3];
    const float* b_proj = (const float*)d_in[4];
    float* out = (float*)d_out;

    unsigned short* qkv_ws = (unsigned short*)d_ws;              // bf16 [8192, 2304]
    const size_t qkv_bytes = (size_t)B_ * T_ * QKV_ROW * sizeof(unsigned short);
    float* lse_ws = (float*)((char*)d_ws + qkv_bytes);           // fp32 [2][98304]
    unsigned short* y_part = (unsigned short*)d_out;             // bf16 [2][8192][768]

    dim3 blk(256);

    // 1) qkv = x @ W_attn + b_attn   (fp32 A, lda=768) -> bf16
    gemm_bias_kernel<false, true><<<dim3(QKV_ROW / 128, (B_ * T_) / 128), blk, 0, stream>>>(
        x, W_attn, b_attn, (void*)qkv_ws, B_ * T_, QKV_ROW, E_, E_);

    // 2) flash attention, paired + 2-way kv parity split -> bf16 partials in d_out
    flash_kernel<<<dim3(T_ / 128, B_ * NH_, 2), blk, 0, stream>>>(qkv_ws, y_part, lse_ws);

    // 3) merge partials -> bf16 y into qkv Q-slots
    merge_kernel<<<dim3(BTE / 8 / 256), blk, 0, stream>>>(y_part, lse_ws, qkv_ws);

    // 4) out = y @ W_proj + b_proj   (bf16 A, lda=2304) -> fp32
    gemm_bias_kernel<true, false><<<dim3(E_ / 128, (B_ * T_) / 128), blk, 0, stream>>>(
        qkv_ws, W_proj, b_proj, (void*)out, B_ * T_, E_, E_, QKV_ROW);
}

// Round 6
// 397.532 us; speedup vs baseline: 1.4846x; 1.0824x over previous
//
#include <hip/hip_runtime.h>
#include <hip/hip_bf16.h>
#include <cmath>

#define B_   2
#define T_   4096
#define E_   768
#define NH_  12
#define HS_  64
#define QKV_ROW (3 * E_)   // 2304
#define LSE_N (B_ * NH_ * T_)   // 98304
#define BTE   (B_ * T_ * E_)    // 6291456

typedef __attribute__((ext_vector_type(8))) short bf16x8;
typedef __attribute__((ext_vector_type(4))) float f32x4;

__device__ __forceinline__ unsigned short f2bf(float f) {
    __hip_bfloat16 h = __float2bfloat16(f);
    return __builtin_bit_cast(unsigned short, h);
}
__device__ __forceinline__ float bf2f(unsigned short s) {
    unsigned int u = (unsigned int)s << 16;
    return __builtin_bit_cast(float, u);
}

// ---------------------------------------------------------------------------
// GEMM: C[M,N] = A[M,K] @ B[K,N] + bias[N].  A fp32 or bf16 (lda-strided).
// 128x128 block tile, 4 waves (2x2), each wave 64x64 via 4x4 mfma 16x16x32 bf16
// ---------------------------------------------------------------------------
template<bool A_BF16, bool OUT_BF16>
__global__ __launch_bounds__(256) void gemm_bias_kernel(
    const void* __restrict__ Ain, const float* __restrict__ Bm,
    const float* __restrict__ bias, void* __restrict__ Cout,
    int M, int N, int K, int lda)
{
    __shared__ __align__(16) unsigned short As[128][40];  // [m][k]
    __shared__ __align__(16) unsigned short Bt[128][40];  // [n][k] (B transposed)

    const int tid  = threadIdx.x;
    const int m0   = blockIdx.y * 128;
    const int n0   = blockIdx.x * 128;
    const int w    = tid >> 6;
    const int lane = tid & 63;
    const int lr   = lane & 15;
    const int lk   = lane >> 4;
    const int wm   = (w >> 1) * 64;
    const int wn   = (w & 1) * 64;

    f32x4 acc[4][4];
#pragma unroll
    for (int i = 0; i < 4; ++i)
#pragma unroll
        for (int j = 0; j < 4; ++j) acc[i][j] = (f32x4){0.f, 0.f, 0.f, 0.f};

    const int ar = tid >> 3;         // 0..31 (A row group)
    const int ak = (tid & 7) * 4;    // 0..28 (A k col)
    const int bn = (tid & 31) * 4;   // 0..124 (B n col)
    const int bk = tid >> 5;         // 0..7  (B k row group)

    for (int k0 = 0; k0 < K; k0 += 32) {
#pragma unroll
        for (int i = 0; i < 4; ++i) {
            const int row = ar + i * 32;
            if (A_BF16) {
                const unsigned short* Ab = (const unsigned short*)Ain;
                *(ushort4*)&As[row][ak] =
                    *(const ushort4*)&Ab[(size_t)(m0 + row) * lda + k0 + ak];
            } else {
                const float* Af = (const float*)Ain;
                const float4 v = *(const float4*)&Af[(size_t)(m0 + row) * lda + k0 + ak];
                ushort4 s;
                s.x = f2bf(v.x); s.y = f2bf(v.y); s.z = f2bf(v.z); s.w = f2bf(v.w);
                *(ushort4*)&As[row][ak] = s;
            }
        }
#pragma unroll
        for (int i = 0; i < 4; ++i) {
            const int k = bk + i * 8;
            const float4 v = *(const float4*)&Bm[(size_t)(k0 + k) * N + n0 + bn];
            Bt[bn + 0][k] = f2bf(v.x);
            Bt[bn + 1][k] = f2bf(v.y);
            Bt[bn + 2][k] = f2bf(v.z);
            Bt[bn + 3][k] = f2bf(v.w);
        }
        __syncthreads();

        bf16x8 a[4], b[4];
#pragma unroll
        for (int i = 0; i < 4; ++i)
            a[i] = *(const bf16x8*)&As[wm + i * 16 + lr][lk * 8];
#pragma unroll
        for (int j = 0; j < 4; ++j)
            b[j] = *(const bf16x8*)&Bt[wn + j * 16 + lr][lk * 8];
#pragma unroll
        for (int i = 0; i < 4; ++i)
#pragma unroll
            for (int j = 0; j < 4; ++j)
                acc[i][j] = __builtin_amdgcn_mfma_f32_16x16x32_bf16(
                    a[i], b[j], acc[i][j], 0, 0, 0);
        __syncthreads();
    }

#pragma unroll
    for (int i = 0; i < 4; ++i) {
#pragma unroll
        for (int j = 0; j < 4; ++j) {
#pragma unroll
            for (int r = 0; r < 4; ++r) {
                const int row = m0 + wm + i * 16 + lk * 4 + r;
                const int col = n0 + wn + j * 16 + lr;
                const float v = acc[i][j][r] + bias[col];
                if (OUT_BF16)
                    ((unsigned short*)Cout)[(size_t)row * N + col] = f2bf(v);
                else
                    ((float*)Cout)[(size_t)row * N + col] = v;
            }
        }
    }
}

// ---------------------------------------------------------------------------
// Flash attention (causal): paired q-tiles + 2-way kv parity split.
// S^T = mfma(K,Q); P stays in REGISTERS via consistent k-permutation
// K(l,j) = (j<4?0:16) + 4*lk + (j&3) + 32*ks on both PV operands.
// T14 async staging: global->reg issue overlapped with previous compute.
// ---------------------------------------------------------------------------
__global__ __launch_bounds__(256) void flash_kernel(
    const unsigned short* __restrict__ qkv,
    unsigned short* __restrict__ y_part,  // [2][B*T][E] bf16 (aliases d_out)
    float* __restrict__ lse)              // [2][B*NH*T]
{
    __shared__ __align__(16) unsigned short K_lds[64][72];    // [kv][hs]
    __shared__ __align__(16) unsigned short Vt[64][72];       // [hs][kv] swizzled

    const int tid  = threadIdx.x;
    const int w    = tid >> 6;
    const int lane = tid & 63;
    const int lr   = lane & 15;
    const int lk   = lane >> 4;
    const int head = blockIdx.y;
    const int z    = blockIdx.z;
    const int b    = head / NH_;
    const int nh   = head % NH_;
    const int qb_lo = blockIdx.x;        // 0..31
    const int qb_hi = 63 - qb_lo;        // 32..63
    const int q0_lo = qb_lo * 64;
    const int q0_hi = qb_hi * 64;

    const unsigned short* qkv_b = qkv + (size_t)b * T_ * QKV_ROW;

    bf16x8 qf_lo[2], qf_hi[2];
    {
        const unsigned short* qrl =
            qkv_b + (size_t)(q0_lo + w * 16 + lr) * QKV_ROW + nh * HS_;
        qf_lo[0] = *(const bf16x8*)(qrl + lk * 8);
        qf_lo[1] = *(const bf16x8*)(qrl + 32 + lk * 8);
        const unsigned short* qrh =
            qkv_b + (size_t)(q0_hi + w * 16 + lr) * QKV_ROW + nh * HS_;
        qf_hi[0] = *(const bf16x8*)(qrh + lk * 8);
        qf_hi[1] = *(const bf16x8*)(qrh + 32 + lk * 8);
    }

    // acc[cb2][r]: hs = cb2*16 + lk*4 + r, q = lr  (Y^T layout)
    f32x4 acc_lo[4], acc_hi[4];
#pragma unroll
    for (int i = 0; i < 4; ++i) {
        acc_lo[i] = (f32x4){0.f, 0.f, 0.f, 0.f};
        acc_hi[i] = (f32x4){0.f, 0.f, 0.f, 0.f};
    }
    float m_lo = -INFINITY, l_lo = 0.f, m_hi = -INFINITY, l_hi = 0.f;

    const int sr = tid >> 2;          // staging row (kv)
    const int sc = (tid & 3) * 16;    // staging col base (hs)

    const float beta = 0.18033688011f;  // (1/sqrt(64)) * log2(e)

    // softmax on S^T fragments; emit P as PV B-fragments (permuted-k order)
    auto softmax_pack = [&](f32x4* st, f32x4* acc, float& m, float& l,
                            int q0, int kv0, bool diag,
                            bf16x8& pf0, bf16x8& pf1) {
        float sv[4][4];
        float mx = -INFINITY;
        const int tq = q0 + w * 16 + lr;
#pragma unroll
        for (int cb = 0; cb < 4; ++cb) {
#pragma unroll
            for (int r = 0; r < 4; ++r) {
                float v = st[cb][r] * beta;
                if (diag) {
                    const int tk = kv0 + cb * 16 + lk * 4 + r;
                    if (tk > tq) v = -INFINITY;
                }
                sv[cb][r] = v;
                mx = fmaxf(mx, v);
            }
        }
        mx = fmaxf(mx, __shfl_xor(mx, 16));
        mx = fmaxf(mx, __shfl_xor(mx, 32));
        const float mnew  = fmaxf(m, mx);
        const float alpha = exp2f(m - mnew);
        m = mnew;
        float rs = 0.f;
        float pv[4][4];
#pragma unroll
        for (int cb = 0; cb < 4; ++cb)
#pragma unroll
            for (int r = 0; r < 4; ++r) {
                pv[cb][r] = exp2f(sv[cb][r] - mnew);
                rs += pv[cb][r];
            }
        rs += __shfl_xor(rs, 16);
        rs += __shfl_xor(rs, 32);
        l = l * alpha + rs;
#pragma unroll
        for (int cb2 = 0; cb2 < 4; ++cb2) acc[cb2] *= alpha;
        // pf0: slots 0..3 = P^T[kv=4lk+r], slots 4..7 = P^T[16+4lk+r] (cb 0,1)
#pragma unroll
        for (int r = 0; r < 4; ++r) {
            pf0[r]     = (short)f2bf(pv[0][r]);
            pf0[r + 4] = (short)f2bf(pv[1][r]);
            pf1[r]     = (short)f2bf(pv[2][r]);
            pf1[r + 4] = (short)f2bf(pv[3][r]);
        }
    };

    // T14 staging registers (next tile in flight)
    int4 k01r, k23r, v01r, v23r;
    auto load_regs = [&](int j) {
        const unsigned short* krow =
            qkv_b + (size_t)(j * 64 + sr) * QKV_ROW + E_ + nh * HS_ + sc;
        const unsigned short* vrow = krow + E_;
        k01r = *(const int4*)krow;
        k23r = *(const int4*)(krow + 8);
        v01r = *(const int4*)vrow;
        v23r = *(const int4*)(vrow + 8);
    };

    load_regs(z);
    for (int j = z; j <= qb_hi; ) {
        const int kv0 = j * 64;
        const bool do_lo = (j <= qb_lo);
        __syncthreads();  // prior tile's LDS reads complete
        {
            *(int4*)&K_lds[sr][sc]     = k01r;
            *(int4*)&K_lds[sr][sc + 8] = k23r;
            const unsigned short* vs0 = (const unsigned short*)&v01r;
            const unsigned short* vs1 = (const unsigned short*)&v23r;
            const int kvhi = sr >> 3, kvlo = sr & 7;
#pragma unroll
            for (int i = 0; i < 8; ++i) {
                const int h = sc + i;
                Vt[h][((kvhi ^ (h >> 3)) << 3) + kvlo] = vs0[i];
            }
#pragma unroll
            for (int i = 0; i < 8; ++i) {
                const int h = sc + 8 + i;
                Vt[h][((kvhi ^ (h >> 3)) << 3) + kvlo] = vs1[i];
            }
        }
        __syncthreads();

        const int jn = j + 2;
        if (jn <= qb_hi) load_regs(jn);   // issue next tile early (T14)

        // K fragments (shared by both q-tiles)
        bf16x8 kf[4][2];
#pragma unroll
        for (int cb = 0; cb < 4; ++cb)
#pragma unroll
            for (int ks = 0; ks < 2; ++ks)
                kf[cb][ks] = *(const bf16x8*)&K_lds[cb * 16 + lr][ks * 32 + lk * 8];

        // V^T fragments in permuted-k order: two b64 reads each
        bf16x8 vf[4][2];
#pragma unroll
        for (int cb2 = 0; cb2 < 4; ++cb2) {
            const int row = cb2 * 16 + lr;
            const int sw  = row >> 3;
#pragma unroll
            for (int ks = 0; ks < 2; ++ks) {
                const int cA = ((4 * ks + (lk >> 1)) ^ sw);
                const int cB = ((4 * ks + 2 + (lk >> 1)) ^ sw);
                const int off = 4 * (lk & 1);
                ushort4 a = *(const ushort4*)&Vt[row][cA * 8 + off];
                ushort4 bq = *(const ushort4*)&Vt[row][cB * 8 + off];
                bf16x8 v;
                v[0] = (short)a.x;  v[1] = (short)a.y;
                v[2] = (short)a.z;  v[3] = (short)a.w;
                v[4] = (short)bq.x; v[5] = (short)bq.y;
                v[6] = (short)bq.z; v[7] = (short)bq.w;
                vf[cb2][ks] = v;
            }
        }

        // S^T = K @ Q^T
        f32x4 st_hi[4], st_lo[4];
        __builtin_amdgcn_s_setprio(1);
#pragma unroll
        for (int cb = 0; cb < 4; ++cb) {
            st_hi[cb] = (f32x4){0.f, 0.f, 0.f, 0.f};
            st_hi[cb] = __builtin_amdgcn_mfma_f32_16x16x32_bf16(kf[cb][0], qf_hi[0], st_hi[cb], 0, 0, 0);
            st_hi[cb] = __builtin_amdgcn_mfma_f32_16x16x32_bf16(kf[cb][1], qf_hi[1], st_hi[cb], 0, 0, 0);
        }
        if (do_lo) {
#pragma unroll
            for (int cb = 0; cb < 4; ++cb) {
                st_lo[cb] = (f32x4){0.f, 0.f, 0.f, 0.f};
                st_lo[cb] = __builtin_amdgcn_mfma_f32_16x16x32_bf16(kf[cb][0], qf_lo[0], st_lo[cb], 0, 0, 0);
                st_lo[cb] = __builtin_amdgcn_mfma_f32_16x16x32_bf16(kf[cb][1], qf_lo[1], st_lo[cb], 0, 0, 0);
            }
        }
        __builtin_amdgcn_s_setprio(0);

        // --- hi: softmax (in-register P) + PV ---
        bf16x8 pf0, pf1;
        softmax_pack(st_hi, acc_hi, m_hi, l_hi, q0_hi, kv0, j == qb_hi, pf0, pf1);
        __builtin_amdgcn_s_setprio(1);
#pragma unroll
        for (int cb2 = 0; cb2 < 4; ++cb2) {
            acc_hi[cb2] = __builtin_amdgcn_mfma_f32_16x16x32_bf16(vf[cb2][0], pf0, acc_hi[cb2], 0, 0, 0);
            acc_hi[cb2] = __builtin_amdgcn_mfma_f32_16x16x32_bf16(vf[cb2][1], pf1, acc_hi[cb2], 0, 0, 0);
        }
        __builtin_amdgcn_s_setprio(0);

        // --- lo: softmax + PV ---
        if (do_lo) {
            softmax_pack(st_lo, acc_lo, m_lo, l_lo, q0_lo, kv0, j == qb_lo, pf0, pf1);
            __builtin_amdgcn_s_setprio(1);
#pragma unroll
            for (int cb2 = 0; cb2 < 4; ++cb2) {
                acc_lo[cb2] = __builtin_amdgcn_mfma_f32_16x16x32_bf16(vf[cb2][0], pf0, acc_lo[cb2], 0, 0, 0);
                acc_lo[cb2] = __builtin_amdgcn_mfma_f32_16x16x32_bf16(vf[cb2][1], pf1, acc_lo[cb2], 0, 0, 0);
            }
            __builtin_amdgcn_s_setprio(0);
        }
        j = jn;
    }

    // store bf16 partials (Y^T layout -> [row][e]) + LSE
    {
        unsigned short* yp = y_part + (size_t)z * BTE;
        const float li_hi = (l_hi > 0.f) ? 1.0f / l_hi : 0.f;
        const float li_lo = (l_lo > 0.f) ? 1.0f / l_lo : 0.f;
        const int tq_hi = q0_hi + w * 16 + lr;
        const int tq_lo = q0_lo + w * 16 + lr;
        unsigned short* yh = &yp[(size_t)(b * T_ + tq_hi) * E_ + nh * HS_];
        unsigned short* yl = &yp[(size_t)(b * T_ + tq_lo) * E_ + nh * HS_];
#pragma unroll
        for (int cb2 = 0; cb2 < 4; ++cb2) {
            ushort4 oh, ol;
            oh.x = f2bf(acc_hi[cb2][0] * li_hi); oh.y = f2bf(acc_hi[cb2][1] * li_hi);
            oh.z = f2bf(acc_hi[cb2][2] * li_hi); oh.w = f2bf(acc_hi[cb2][3] * li_hi);
            ol.x = f2bf(acc_lo[cb2][0] * li_lo); ol.y = f2bf(acc_lo[cb2][1] * li_lo);
            ol.z = f2bf(acc_lo[cb2][2] * li_lo); ol.w = f2bf(acc_lo[cb2][3] * li_lo);
            *(ushort4*)&yh[cb2 * 16 + lk * 4] = oh;
            *(ushort4*)&yl[cb2 * 16 + lk * 4] = ol;
        }
        if (lk == 0) {
            float* lz = lse + (size_t)z * LSE_N + (size_t)head * T_;
            lz[tq_hi] = (l_hi > 0.f) ? (m_hi + log2f(l_hi)) : -1e30f;
            lz[tq_lo] = (l_lo > 0.f) ? (m_lo + log2f(l_lo)) : -1e30f;
        }
    }
}

// ---------------------------------------------------------------------------
// Merge the two kv-split partials; write bf16 y into the (dead) Q-slots of qkv.
// ---------------------------------------------------------------------------
__global__ __launch_bounds__(256) void merge_kernel(
    const unsigned short* __restrict__ y_part,  // [2][B*T][E] bf16
    const float* __restrict__ lse,              // [2][B*NH*T]
    unsigned short* __restrict__ qkv)           // y -> qkv[row][0:768]
{
    const int i  = blockIdx.x * 256 + threadIdx.x;   // 8-elem group
    const int e0 = i * 8;
    const int row = e0 / E_;            // b*T + t
    const int e   = e0 - row * E_;
    const int nh  = e >> 6;
    const int lidx = ((row >> 12) * NH_ + nh) * T_ + (row & (T_ - 1));
    const float s0 = lse[lidx];
    const float s1 = lse[LSE_N + lidx];
    const float M  = fmaxf(s0, s1);
    float w0 = exp2f(s0 - M), w1 = exp2f(s1 - M);
    const float inv = 1.0f / (w0 + w1);
    w0 *= inv; w1 *= inv;
    bf16x8 p0 = *(const bf16x8*)&y_part[e0];
    bf16x8 p1 = *(const bf16x8*)&y_part[(size_t)BTE + e0];
    ushort4 oa, ob;
    unsigned short o[8];
#pragma unroll
    for (int jj = 0; jj < 8; ++jj)
        o[jj] = f2bf(w0 * bf2f((unsigned short)p0[jj]) +
                     w1 * bf2f((unsigned short)p1[jj]));
    oa.x = o[0]; oa.y = o[1]; oa.z = o[2]; oa.w = o[3];
    ob.x = o[4]; ob.y = o[5]; ob.z = o[6]; ob.w = o[7];
    unsigned short* dst = &qkv[(size_t)row * QKV_ROW + e];
    *(ushort4*)dst = oa;
    *(ushort4*)(dst + 4) = ob;
}

// ---------------------------------------------------------------------------
extern "C" void kernel_launch(void* const* d_in, const int* in_sizes, int n_in,
                              void* d_out, int out_size, void* d_ws, size_t ws_size,
                              hipStream_t stream)
{
    const float* x      = (const float*)d_in[0];
    const float* W_attn = (const float*)d_in[1];
    const float* b_attn = (const float*)d_in[2];
    const float* W_proj = (const float*)d_in[3];
    const float* b_proj = (const float*)d_in[4];
    float* out = (float*)d_out;

    unsigned short* qkv_ws = (unsigned short*)d_ws;              // bf16 [8192, 2304]
    const size_t qkv_bytes = (size_t)B_ * T_ * QKV_ROW * sizeof(unsigned short);
    float* lse_ws = (float*)((char*)d_ws + qkv_bytes);           // fp32 [2][98304]
    unsigned short* y_part = (unsigned short*)d_out;             // bf16 [2][8192][768]

    dim3 blk(256);

    // 1) qkv = x @ W_attn + b_attn   (fp32 A, lda=768) -> bf16
    gemm_bias_kernel<false, true><<<dim3(QKV_ROW / 128, (B_ * T_) / 128), blk, 0, stream>>>(
        x, W_attn, b_attn, (void*)qkv_ws, B_ * T_, QKV_ROW, E_, E_);

    // 2) flash attention, paired + 2-way kv parity split -> bf16 partials in d_out
    flash_kernel<<<dim3(T_ / 128, B_ * NH_, 2), blk, 0, stream>>>(qkv_ws, y_part, lse_ws);

    // 3) merge partials -> bf16 y into qkv Q-slots
    merge_kernel<<<dim3(BTE / 8 / 256), blk, 0, stream>>>(y_part, lse_ws, qkv_ws);

    // 4) out = y @ W_proj + b_proj   (bf16 A, lda=2304) -> fp32
    gemm_bias_kernel<true, false><<<dim3(E_ / 128, (B_ * T_) / 128), blk, 0, stream>>>(
        qkv_ws, W_proj, b_proj, (void*)out, B_ * T_, E_, E_, QKV_ROW);
}

// Round 7
// 267.980 us; speedup vs baseline: 2.2024x; 1.4834x over previous
//
#include <hip/hip_runtime.h>
#include <hip/hip_bf16.h>
#include <cmath>

#define B_   2
#define T_   4096
#define E_   768
#define NH_  12
#define HS_  64
#define QKV_ROW (3 * E_)   // 2304
#define LSE_N (B_ * NH_ * T_)   // 98304
#define BTE   (B_ * T_ * E_)    // 6291456

typedef __attribute__((ext_vector_type(8))) short bf16x8;
typedef __attribute__((ext_vector_type(4))) float f32x4;

__device__ __forceinline__ unsigned short f2bf(float f) {
    __hip_bfloat16 h = __float2bfloat16(f);
    return __builtin_bit_cast(unsigned short, h);
}
__device__ __forceinline__ float bf2f(unsigned short s) {
    unsigned int u = (unsigned int)s << 16;
    return __builtin_bit_cast(float, u);
}

#define GLOAD16(gptr, lptr)                                             \
    __builtin_amdgcn_global_load_lds(                                   \
        (const __attribute__((address_space(1))) void*)(gptr),          \
        (__attribute__((address_space(3))) void*)(lptr), 16, 0, 0)

// ---------------------------------------------------------------------------
// x fp32 -> bf16 (elementwise)
// ---------------------------------------------------------------------------
__global__ __launch_bounds__(256) void cvt_x_kernel(
    const float* __restrict__ x, unsigned short* __restrict__ xb)
{
    const int i = (blockIdx.x * 256 + threadIdx.x) * 8;
    const float4 v0 = *(const float4*)&x[i];
    const float4 v1 = *(const float4*)&x[i + 4];
    unsigned short o[8];
    o[0] = f2bf(v0.x); o[1] = f2bf(v0.y); o[2] = f2bf(v0.z); o[3] = f2bf(v0.w);
    o[4] = f2bf(v1.x); o[5] = f2bf(v1.y); o[6] = f2bf(v1.z); o[7] = f2bf(v1.w);
    *(int4*)&xb[i] = *(const int4*)o;
}

// ---------------------------------------------------------------------------
// W fp32 [K][N] -> Wt bf16 [N][K]  (LDS-tiled transpose, 64x64 per block)
// ---------------------------------------------------------------------------
__global__ __launch_bounds__(256) void transpose_w_kernel(
    const float* __restrict__ W, unsigned short* __restrict__ Wt, int K, int N)
{
    __shared__ float tile[64][65];
    const int k0  = blockIdx.y * 64;
    const int n0  = blockIdx.x * 64;
    const int tid = threadIdx.x;
    const int tc  = tid & 15;
    const int tr  = tid >> 4;
#pragma unroll
    for (int i = 0; i < 4; ++i) {
        const int k = tr + i * 16;
        const float4 v = *(const float4*)&W[(size_t)(k0 + k) * N + n0 + tc * 4];
        tile[k][tc * 4 + 0] = v.x; tile[k][tc * 4 + 1] = v.y;
        tile[k][tc * 4 + 2] = v.z; tile[k][tc * 4 + 3] = v.w;
    }
    __syncthreads();
    const int nr = tid >> 2;          // 0..63 out row (n)
    const int kc = (tid & 3) * 16;    // 16 k's per thread
    unsigned short o[16];
#pragma unroll
    for (int j = 0; j < 16; ++j) o[j] = f2bf(tile[kc + j][nr]);
    unsigned short* dst = &Wt[(size_t)(n0 + nr) * K + k0 + kc];
    *(int4*)dst       = *(const int4*)&o[0];
    *(int4*)(dst + 8) = *(const int4*)&o[8];
}

// ---------------------------------------------------------------------------
// GEMM (m97 structure): C[M,N] = A[M,K]bf16 @ Bt[N,K]bf16^T + bias.
// 128x128 tile, BK=64, global_load_lds w16 with pre-swizzled source,
// swizzled ds_read_b128 fragments. QSCALE: cols<768 scaled by beta (Q).
// ---------------------------------------------------------------------------
template<bool OUT_BF16, bool QSCALE>
__global__ __launch_bounds__(256) void gemm_bt_kernel(
    const unsigned short* __restrict__ A,   // [M][lda]
    const unsigned short* __restrict__ Bt,  // [N][K]
    const float* __restrict__ bias, void* __restrict__ Cout,
    int M, int N, int K, int lda)
{
    __shared__ __align__(16) unsigned short Als[128 * 64];
    __shared__ __align__(16) unsigned short Bls[128 * 64];

    const int tid  = threadIdx.x;
    const int m0   = blockIdx.y * 128;
    const int n0   = blockIdx.x * 128;
    const int w    = tid >> 6;
    const int lane = tid & 63;
    const int lr   = lane & 15;
    const int lk   = lane >> 4;
    const int wm   = (w >> 1) * 64;
    const int wn   = (w & 1) * 64;

    f32x4 acc[4][4];
#pragma unroll
    for (int i = 0; i < 4; ++i)
#pragma unroll
        for (int j = 0; j < 4; ++j) acc[i][j] = (f32x4){0.f, 0.f, 0.f, 0.f};

    for (int k0 = 0; k0 < K; k0 += 64) {
        __syncthreads();   // previous iteration's fragment reads complete
#pragma unroll
        for (int c = 0; c < 4; ++c) {
            const int idx = c * 256 + tid;
            const int row = idx >> 3;
            const int g   = (tid & 7) ^ (row & 7);   // inverse-swizzled source
            GLOAD16(&A[(size_t)(m0 + row) * lda + k0 + g * 8], &Als[idx * 8]);
        }
#pragma unroll
        for (int c = 0; c < 4; ++c) {
            const int idx = c * 256 + tid;
            const int row = idx >> 3;
            const int g   = (tid & 7) ^ (row & 7);
            GLOAD16(&Bt[(size_t)(n0 + row) * K + k0 + g * 8], &Bls[idx * 8]);
        }
        __syncthreads();   // compiler drains vmcnt before barrier

#pragma unroll
        for (int kk = 0; kk < 2; ++kk) {
            bf16x8 a[4], b[4];
            const int gp = ((kk * 4 + lk) ^ (lr & 7)) << 3;
#pragma unroll
            for (int i = 0; i < 4; ++i) {
                a[i] = *(const bf16x8*)&Als[(wm + i * 16 + lr) * 64 + gp];
                b[i] = *(const bf16x8*)&Bls[(wn + i * 16 + lr) * 64 + gp];
            }
#pragma unroll
            for (int i = 0; i < 4; ++i)
#pragma unroll
                for (int j = 0; j < 4; ++j)
                    acc[i][j] = __builtin_amdgcn_mfma_f32_16x16x32_bf16(
                        a[i], b[j], acc[i][j], 0, 0, 0);
        }
    }

    const float beta = 0.18033688011f;  // (1/sqrt(64)) * log2(e)
#pragma unroll
    for (int i = 0; i < 4; ++i) {
#pragma unroll
        for (int j = 0; j < 4; ++j) {
            const int col = n0 + wn + j * 16 + lr;
#pragma unroll
            for (int r = 0; r < 4; ++r) {
                const int row = m0 + wm + i * 16 + lk * 4 + r;
                float v = acc[i][j][r] + bias[col];
                if (QSCALE && col < E_) v *= beta;
                if (OUT_BF16)
                    ((unsigned short*)Cout)[(size_t)row * N + col] = f2bf(v);
                else
                    ((float*)Cout)[(size_t)row * N + col] = v;
            }
        }
    }
}

// ---------------------------------------------------------------------------
// Flash attention (causal): paired q-tiles + 2-way kv parity split.
// S^T = mfma(K,Q) with Q pre-scaled by beta; P stays in registers via the
// consistent k-permutation on both PV operands. T14 async staging.
// ---------------------------------------------------------------------------
__global__ __launch_bounds__(256) void flash_kernel(
    const unsigned short* __restrict__ qkv,
    unsigned short* __restrict__ y_part,  // [2][B*T][E] bf16 (aliases d_out)
    float* __restrict__ lse)              // [2][B*NH*T]
{
    __shared__ __align__(16) unsigned short K_lds[64][72];    // [kv][hs]
    __shared__ __align__(16) unsigned short Vt[64][72];       // [hs][kv] swizzled

    const int tid  = threadIdx.x;
    const int w    = tid >> 6;
    const int lane = tid & 63;
    const int lr   = lane & 15;
    const int lk   = lane >> 4;
    const int head = blockIdx.y;
    const int z    = blockIdx.z;
    const int b    = head / NH_;
    const int nh   = head % NH_;
    const int qb_lo = blockIdx.x;        // 0..31
    const int qb_hi = 63 - qb_lo;        // 32..63
    const int q0_lo = qb_lo * 64;
    const int q0_hi = qb_hi * 64;

    const unsigned short* qkv_b = qkv + (size_t)b * T_ * QKV_ROW;

    bf16x8 qf_lo[2], qf_hi[2];
    {
        const unsigned short* qrl =
            qkv_b + (size_t)(q0_lo + w * 16 + lr) * QKV_ROW + nh * HS_;
        qf_lo[0] = *(const bf16x8*)(qrl + lk * 8);
        qf_lo[1] = *(const bf16x8*)(qrl + 32 + lk * 8);
        const unsigned short* qrh =
            qkv_b + (size_t)(q0_hi + w * 16 + lr) * QKV_ROW + nh * HS_;
        qf_hi[0] = *(const bf16x8*)(qrh + lk * 8);
        qf_hi[1] = *(const bf16x8*)(qrh + 32 + lk * 8);
    }

    f32x4 acc_lo[4], acc_hi[4];
#pragma unroll
    for (int i = 0; i < 4; ++i) {
        acc_lo[i] = (f32x4){0.f, 0.f, 0.f, 0.f};
        acc_hi[i] = (f32x4){0.f, 0.f, 0.f, 0.f};
    }
    float m_lo = -INFINITY, l_lo = 0.f, m_hi = -INFINITY, l_hi = 0.f;

    const int sr = tid >> 2;          // staging row (kv)
    const int sc = (tid & 3) * 16;    // staging col base (hs)

    // softmax on S^T fragments; emit P as PV B-fragments (permuted-k order)
    auto softmax_pack = [&](f32x4* st, f32x4* acc, float& m, float& l,
                            int q0, int kv0, bool diag,
                            bf16x8& pf0, bf16x8& pf1) {
        float sv[4][4];
        float mx = -INFINITY;
        const int tq = q0 + w * 16 + lr;
#pragma unroll
        for (int cb = 0; cb < 4; ++cb) {
#pragma unroll
            for (int r = 0; r < 4; ++r) {
                float v = st[cb][r];
                if (diag) {
                    const int tk = kv0 + cb * 16 + lk * 4 + r;
                    if (tk > tq) v = -INFINITY;
                }
                sv[cb][r] = v;
                mx = fmaxf(mx, v);
            }
        }
        mx = fmaxf(mx, __shfl_xor(mx, 16));
        mx = fmaxf(mx, __shfl_xor(mx, 32));
        const float mnew  = fmaxf(m, mx);
        const float alpha = exp2f(m - mnew);
        m = mnew;
        float rs = 0.f;
        float pv[4][4];
#pragma unroll
        for (int cb = 0; cb < 4; ++cb)
#pragma unroll
            for (int r = 0; r < 4; ++r) {
                pv[cb][r] = exp2f(sv[cb][r] - mnew);
                rs += pv[cb][r];
            }
        rs += __shfl_xor(rs, 16);
        rs += __shfl_xor(rs, 32);
        l = l * alpha + rs;
#pragma unroll
        for (int cb2 = 0; cb2 < 4; ++cb2) acc[cb2] *= alpha;
#pragma unroll
        for (int r = 0; r < 4; ++r) {
            pf0[r]     = (short)f2bf(pv[0][r]);
            pf0[r + 4] = (short)f2bf(pv[1][r]);
            pf1[r]     = (short)f2bf(pv[2][r]);
            pf1[r + 4] = (short)f2bf(pv[3][r]);
        }
    };

    // T14 staging registers (next tile in flight)
    int4 k01r, k23r, v01r, v23r;
    auto load_regs = [&](int j) {
        const unsigned short* krow =
            qkv_b + (size_t)(j * 64 + sr) * QKV_ROW + E_ + nh * HS_ + sc;
        const unsigned short* vrow = krow + E_;
        k01r = *(const int4*)krow;
        k23r = *(const int4*)(krow + 8);
        v01r = *(const int4*)vrow;
        v23r = *(const int4*)(vrow + 8);
    };

    load_regs(z);
    for (int j = z; j <= qb_hi; ) {
        const int kv0 = j * 64;
        const bool do_lo = (j <= qb_lo);
        __syncthreads();
        {
            *(int4*)&K_lds[sr][sc]     = k01r;
            *(int4*)&K_lds[sr][sc + 8] = k23r;
            const unsigned short* vs0 = (const unsigned short*)&v01r;
            const unsigned short* vs1 = (const unsigned short*)&v23r;
            const int kvhi = sr >> 3, kvlo = sr & 7;
#pragma unroll
            for (int i = 0; i < 8; ++i) {
                const int h = sc + i;
                Vt[h][((kvhi ^ (h >> 3)) << 3) + kvlo] = vs0[i];
            }
#pragma unroll
            for (int i = 0; i < 8; ++i) {
                const int h = sc + 8 + i;
                Vt[h][((kvhi ^ (h >> 3)) << 3) + kvlo] = vs1[i];
            }
        }
        __syncthreads();

        const int jn = j + 2;
        if (jn <= qb_hi) load_regs(jn);

        bf16x8 kf[4][2];
#pragma unroll
        for (int cb = 0; cb < 4; ++cb)
#pragma unroll
            for (int ks = 0; ks < 2; ++ks)
                kf[cb][ks] = *(const bf16x8*)&K_lds[cb * 16 + lr][ks * 32 + lk * 8];

        bf16x8 vf[4][2];
#pragma unroll
        for (int cb2 = 0; cb2 < 4; ++cb2) {
            const int row = cb2 * 16 + lr;
            const int sw  = row >> 3;
#pragma unroll
            for (int ks = 0; ks < 2; ++ks) {
                const int cA = ((4 * ks + (lk >> 1)) ^ sw);
                const int cB = ((4 * ks + 2 + (lk >> 1)) ^ sw);
                const int off = 4 * (lk & 1);
                ushort4 a = *(const ushort4*)&Vt[row][cA * 8 + off];
                ushort4 bq = *(const ushort4*)&Vt[row][cB * 8 + off];
                bf16x8 v;
                v[0] = (short)a.x;  v[1] = (short)a.y;
                v[2] = (short)a.z;  v[3] = (short)a.w;
                v[4] = (short)bq.x; v[5] = (short)bq.y;
                v[6] = (short)bq.z; v[7] = (short)bq.w;
                vf[cb2][ks] = v;
            }
        }

        f32x4 st_hi[4], st_lo[4];
        __builtin_amdgcn_s_setprio(1);
#pragma unroll
        for (int cb = 0; cb < 4; ++cb) {
            st_hi[cb] = (f32x4){0.f, 0.f, 0.f, 0.f};
            st_hi[cb] = __builtin_amdgcn_mfma_f32_16x16x32_bf16(kf[cb][0], qf_hi[0], st_hi[cb], 0, 0, 0);
            st_hi[cb] = __builtin_amdgcn_mfma_f32_16x16x32_bf16(kf[cb][1], qf_hi[1], st_hi[cb], 0, 0, 0);
        }
        if (do_lo) {
#pragma unroll
            for (int cb = 0; cb < 4; ++cb) {
                st_lo[cb] = (f32x4){0.f, 0.f, 0.f, 0.f};
                st_lo[cb] = __builtin_amdgcn_mfma_f32_16x16x32_bf16(kf[cb][0], qf_lo[0], st_lo[cb], 0, 0, 0);
                st_lo[cb] = __builtin_amdgcn_mfma_f32_16x16x32_bf16(kf[cb][1], qf_lo[1], st_lo[cb], 0, 0, 0);
            }
        }
        __builtin_amdgcn_s_setprio(0);

        bf16x8 pf0, pf1;
        softmax_pack(st_hi, acc_hi, m_hi, l_hi, q0_hi, kv0, j == qb_hi, pf0, pf1);
        __builtin_amdgcn_s_setprio(1);
#pragma unroll
        for (int cb2 = 0; cb2 < 4; ++cb2) {
            acc_hi[cb2] = __builtin_amdgcn_mfma_f32_16x16x32_bf16(vf[cb2][0], pf0, acc_hi[cb2], 0, 0, 0);
            acc_hi[cb2] = __builtin_amdgcn_mfma_f32_16x16x32_bf16(vf[cb2][1], pf1, acc_hi[cb2], 0, 0, 0);
        }
        __builtin_amdgcn_s_setprio(0);

        if (do_lo) {
            softmax_pack(st_lo, acc_lo, m_lo, l_lo, q0_lo, kv0, j == qb_lo, pf0, pf1);
            __builtin_amdgcn_s_setprio(1);
#pragma unroll
            for (int cb2 = 0; cb2 < 4; ++cb2) {
                acc_lo[cb2] = __builtin_amdgcn_mfma_f32_16x16x32_bf16(vf[cb2][0], pf0, acc_lo[cb2], 0, 0, 0);
                acc_lo[cb2] = __builtin_amdgcn_mfma_f32_16x16x32_bf16(vf[cb2][1], pf1, acc_lo[cb2], 0, 0, 0);
            }
            __builtin_amdgcn_s_setprio(0);
        }
        j = jn;
    }

    {
        unsigned short* yp = y_part + (size_t)z * BTE;
        const float li_hi = (l_hi > 0.f) ? 1.0f / l_hi : 0.f;
        const float li_lo = (l_lo > 0.f) ? 1.0f / l_lo : 0.f;
        const int tq_hi = q0_hi + w * 16 + lr;
        const int tq_lo = q0_lo + w * 16 + lr;
        unsigned short* yh = &yp[(size_t)(b * T_ + tq_hi) * E_ + nh * HS_];
        unsigned short* yl = &yp[(size_t)(b * T_ + tq_lo) * E_ + nh * HS_];
#pragma unroll
        for (int cb2 = 0; cb2 < 4; ++cb2) {
            ushort4 oh, ol;
            oh.x = f2bf(acc_hi[cb2][0] * li_hi); oh.y = f2bf(acc_hi[cb2][1] * li_hi);
            oh.z = f2bf(acc_hi[cb2][2] * li_hi); oh.w = f2bf(acc_hi[cb2][3] * li_hi);
            ol.x = f2bf(acc_lo[cb2][0] * li_lo); ol.y = f2bf(acc_lo[cb2][1] * li_lo);
            ol.z = f2bf(acc_lo[cb2][2] * li_lo); ol.w = f2bf(acc_lo[cb2][3] * li_lo);
            *(ushort4*)&yh[cb2 * 16 + lk * 4] = oh;
            *(ushort4*)&yl[cb2 * 16 + lk * 4] = ol;
        }
        if (lk == 0) {
            float* lz = lse + (size_t)z * LSE_N + (size_t)head * T_;
            lz[tq_hi] = (l_hi > 0.f) ? (m_hi + log2f(l_hi)) : -1e30f;
            lz[tq_lo] = (l_lo > 0.f) ? (m_lo + log2f(l_lo)) : -1e30f;
        }
    }
}

// ---------------------------------------------------------------------------
// Merge the two kv-split partials; write bf16 y into the (dead) Q-slots of qkv.
// ---------------------------------------------------------------------------
__global__ __launch_bounds__(256) void merge_kernel(
    const unsigned short* __restrict__ y_part,  // [2][B*T][E] bf16
    const float* __restrict__ lse,              // [2][B*NH*T]
    unsigned short* __restrict__ qkv)           // y -> qkv[row][0:768]
{
    const int i  = blockIdx.x * 256 + threadIdx.x;   // 8-elem group
    const int e0 = i * 8;
    const int row = e0 / E_;            // b*T + t
    const int e   = e0 - row * E_;
    const int nh  = e >> 6;
    const int lidx = ((row >> 12) * NH_ + nh) * T_ + (row & (T_ - 1));
    const float s0 = lse[lidx];
    const float s1 = lse[LSE_N + lidx];
    const float M  = fmaxf(s0, s1);
    float w0 = exp2f(s0 - M), w1 = exp2f(s1 - M);
    const float inv = 1.0f / (w0 + w1);
    w0 *= inv; w1 *= inv;
    bf16x8 p0 = *(const bf16x8*)&y_part[e0];
    bf16x8 p1 = *(const bf16x8*)&y_part[(size_t)BTE + e0];
    ushort4 oa, ob;
    unsigned short o[8];
#pragma unroll
    for (int jj = 0; jj < 8; ++jj)
        o[jj] = f2bf(w0 * bf2f((unsigned short)p0[jj]) +
                     w1 * bf2f((unsigned short)p1[jj]));
    oa.x = o[0]; oa.y = o[1]; oa.z = o[2]; oa.w = o[3];
    ob.x = o[4]; ob.y = o[5]; ob.z = o[6]; ob.w = o[7];
    unsigned short* dst = &qkv[(size_t)row * QKV_ROW + e];
    *(ushort4*)dst = oa;
    *(ushort4*)(dst + 4) = ob;
}

// ---------------------------------------------------------------------------
extern "C" void kernel_launch(void* const* d_in, const int* in_sizes, int n_in,
                              void* d_out, int out_size, void* d_ws, size_t ws_size,
                              hipStream_t stream)
{
    const float* x      = (const float*)d_in[0];
    const float* W_attn = (const float*)d_in[1];
    const float* b_attn = (const float*)d_in[2];
    const float* W_proj = (const float*)d_in[3];
    const float* b_proj = (const float*)d_in[4];
    float* out = (float*)d_out;

    char* ws = (char*)d_ws;
    unsigned short* qkv_ws  = (unsigned short*)ws;                    // 37,748,736 B
    float*          lse_ws  = (float*)(ws + 37748736);                //    786,432 B
    unsigned short* x_bf16  = (unsigned short*)(ws + 38535168);       // 12,582,912 B
    unsigned short* wt_attn = (unsigned short*)(ws + 51118080);       //  3,538,944 B
    unsigned short* wt_proj = (unsigned short*)(ws + 54657024);       //  1,179,648 B
    unsigned short* y_part  = (unsigned short*)d_out;                 // bf16 [2][8192][768]

    dim3 blk(256);

    // 0) one-shot operand prep
    cvt_x_kernel<<<dim3(BTE / 8 / 256), blk, 0, stream>>>(x, x_bf16);
    transpose_w_kernel<<<dim3(QKV_ROW / 64, E_ / 64), blk, 0, stream>>>(W_attn, wt_attn, E_, QKV_ROW);
    transpose_w_kernel<<<dim3(E_ / 64, E_ / 64), blk, 0, stream>>>(W_proj, wt_proj, E_, E_);

    // 1) qkv = x @ W_attn + b_attn  (Q cols pre-scaled by beta) -> bf16
    gemm_bt_kernel<true, true><<<dim3(QKV_ROW / 128, (B_ * T_) / 128), blk, 0, stream>>>(
        x_bf16, wt_attn, b_attn, (void*)qkv_ws, B_ * T_, QKV_ROW, E_, E_);

    // 2) flash attention, paired + 2-way kv parity split -> bf16 partials in d_out
    flash_kernel<<<dim3(T_ / 128, B_ * NH_, 2), blk, 0, stream>>>(qkv_ws, y_part, lse_ws);

    // 3) merge partials -> bf16 y into qkv Q-slots
    merge_kernel<<<dim3(BTE / 8 / 256), blk, 0, stream>>>(y_part, lse_ws, qkv_ws);

    // 4) out = y @ W_proj + b_proj -> fp32
    gemm_bt_kernel<false, false><<<dim3(E_ / 128, (B_ * T_) / 128), blk, 0, stream>>>(
        qkv_ws, wt_proj, b_proj, (void*)out, B_ * T_, E_, E_, QKV_ROW);
}